// Round 1
// baseline (11381.939 us; speedup 1.0000x reference)
//
#include <hip/hip_runtime.h>
#include <math.h>

constexpr int NN   = 100000;
constexpr int FIN  = 128;
constexpr int FHID = 256;
constexpr int FOUT = 40;

// ---------------------------------------------------------------------------
// Dense GEMM: C[M x NC] = act(A[M x 128] @ W[128 x NC] + bias), 64x64 tiles.
// K=128 staged entirely in LDS; W stored transposed so inner loop reads both
// operands as float4 (ds_read_b128).
// ---------------------------------------------------------------------------
template<int K, bool RELU_OUT, bool HAS_BIAS>
__global__ __launch_bounds__(256) void gemm64(
    const float* __restrict__ A, const float* __restrict__ W,
    const float* __restrict__ bias, float* __restrict__ C, int M, int NC)
{
    __shared__ float As[64][K + 4];
    __shared__ float Wt[64][K + 4];
    const int t = threadIdx.x;
    const int brow = blockIdx.x * 64;
    const int bcol = blockIdx.y * 64;

    // load A tile (64 x K) as float4
    #pragma unroll
    for (int i = 0; i < (64 * K) / (256 * 4); ++i) {
        int idx = (t + i * 256) * 4;
        int r = idx / K, c = idx % K;
        int gr = brow + r;
        float4 v = make_float4(0.f, 0.f, 0.f, 0.f);
        if (gr < M) v = *reinterpret_cast<const float4*>(&A[(size_t)gr * K + c]);
        *reinterpret_cast<float4*>(&As[r][c]) = v;
    }
    // load W tile (K x 64) transposed -> Wt[c][k]
    #pragma unroll
    for (int i = 0; i < (64 * K) / (256 * 4); ++i) {
        int idx = (t + i * 256) * 4;
        int k = idx / 64, c = idx % 64;
        float4 v = *reinterpret_cast<const float4*>(&W[(size_t)k * NC + bcol + c]);
        Wt[c + 0][k] = v.x; Wt[c + 1][k] = v.y; Wt[c + 2][k] = v.z; Wt[c + 3][k] = v.w;
    }
    __syncthreads();

    const int tx = t & 15, ty = t >> 4;
    float acc[4][4] = {};
    for (int k = 0; k < K; k += 4) {
        float4 a4[4], b4[4];
        #pragma unroll
        for (int i = 0; i < 4; ++i) a4[i] = *reinterpret_cast<const float4*>(&As[ty + 16 * i][k]);
        #pragma unroll
        for (int j = 0; j < 4; ++j) b4[j] = *reinterpret_cast<const float4*>(&Wt[tx + 16 * j][k]);
        #pragma unroll
        for (int i = 0; i < 4; ++i)
            #pragma unroll
            for (int j = 0; j < 4; ++j) {
                acc[i][j] += a4[i].x * b4[j].x;
                acc[i][j] += a4[i].y * b4[j].y;
                acc[i][j] += a4[i].z * b4[j].z;
                acc[i][j] += a4[i].w * b4[j].w;
            }
    }

    #pragma unroll
    for (int i = 0; i < 4; ++i) {
        int gr = brow + ty + 16 * i;
        if (gr >= M) continue;
        #pragma unroll
        for (int j = 0; j < 4; ++j) {
            int gc = bcol + tx + 16 * j;
            float v = acc[i][j];
            if (HAS_BIAS) v += bias[gc];
            if (RELU_OUT) v = fmaxf(v, 0.f);
            C[(size_t)gr * NC + gc] = v;
        }
    }
}

// ---------------------------------------------------------------------------
// Final GEMM: C[M x 40] = relu(A[M x 256] + b0) @ W1[256 x 40]
// 32 rows/block; full W1 transposed in LDS.
// ---------------------------------------------------------------------------
__global__ __launch_bounds__(256) void gemm_out40(
    const float* __restrict__ A, const float* __restrict__ b0,
    const float* __restrict__ W1, float* __restrict__ C)
{
    __shared__ float As[32][260];
    __shared__ float Wt[40][260];
    const int t = threadIdx.x;
    const int brow = blockIdx.x * 32;

    #pragma unroll
    for (int i = 0; i < 8; ++i) {
        int idx = (t + i * 256) * 4;
        int r = idx >> 8, c = idx & 255;
        float4 v = *reinterpret_cast<const float4*>(&A[(size_t)(brow + r) * 256 + c]);
        v.x = fmaxf(v.x + b0[c + 0], 0.f);
        v.y = fmaxf(v.y + b0[c + 1], 0.f);
        v.z = fmaxf(v.z + b0[c + 2], 0.f);
        v.w = fmaxf(v.w + b0[c + 3], 0.f);
        *reinterpret_cast<float4*>(&As[r][c]) = v;
    }
    #pragma unroll
    for (int i = 0; i < 10; ++i) {
        int idx = (t + i * 256) * 4;
        int k = idx / 40, c = idx % 40;
        float4 v = *reinterpret_cast<const float4*>(&W1[idx]);
        Wt[c + 0][k] = v.x; Wt[c + 1][k] = v.y; Wt[c + 2][k] = v.z; Wt[c + 3][k] = v.w;
    }
    __syncthreads();

    const int tx = t & 7, ty = t >> 3;   // tx: 8 col groups, ty: 32 rows
    float acc[5] = {};
    for (int k = 0; k < 256; k += 4) {
        float4 a = *reinterpret_cast<const float4*>(&As[ty][k]);
        #pragma unroll
        for (int j = 0; j < 5; ++j) {
            float4 b = *reinterpret_cast<const float4*>(&Wt[tx + 8 * j][k]);
            acc[j] += a.x * b.x + a.y * b.y + a.z * b.z + a.w * b.w;
        }
    }
    const int gr = brow + ty;
    #pragma unroll
    for (int j = 0; j < 5; ++j)
        C[(size_t)gr * 40 + tx + 8 * j] = acc[j];
}

// ---------------------------------------------------------------------------
// COO SpMM scatter, F=256: one wave per edge, float4-gather + 4 atomics/lane.
// ---------------------------------------------------------------------------
__global__ __launch_bounds__(256) void spmm_f256(
    const int* __restrict__ rows, const int* __restrict__ cols,
    const float* __restrict__ val, const float* __restrict__ mat,
    float* __restrict__ out, int E)
{
    int gw = (int)((blockIdx.x * 256 + threadIdx.x) >> 6);
    int lane = threadIdx.x & 63;
    if (gw >= E) return;
    int r = rows[gw], c = cols[gw];
    float v = val[gw];
    float4 f = reinterpret_cast<const float4*>(mat + (size_t)c * 256)[lane];
    float* dst = out + (size_t)r * 256 + lane * 4;
    unsafeAtomicAdd(dst + 0, v * f.x);
    unsafeAtomicAdd(dst + 1, v * f.y);
    unsafeAtomicAdd(dst + 2, v * f.z);
    unsafeAtomicAdd(dst + 3, v * f.w);
}

// COO SpMM scatter, F=40: thread per (edge, feature).
__global__ __launch_bounds__(256) void spmm_f40(
    const int* __restrict__ rows, const int* __restrict__ cols,
    const float* __restrict__ val, const float* __restrict__ mat,
    float* __restrict__ out, int E)
{
    long long idx = (long long)blockIdx.x * 256 + threadIdx.x;
    if (idx >= (long long)E * 40) return;
    int e = (int)(idx / 40);
    int f = (int)(idx % 40);
    unsafeAtomicAdd(out + (size_t)rows[e] * 40 + f, val[e] * mat[(size_t)cols[e] * 40 + f]);
}

// ---------------------------------------------------------------------------
// Sampling + l2 partial reduction.
// mean = zx[:, :128]; std = softplus(zx[:, 128:]) + 0.01; h = mean + std*eps
// per-element logq - logp = 0.5*h^2 - 0.5*eps^2 - log(std)   (constants cancel)
// ---------------------------------------------------------------------------
__global__ __launch_bounds__(256) void sample_kernel(
    const float* __restrict__ zx, const float* __restrict__ eps,
    float* __restrict__ h, double* __restrict__ l2acc)
{
    const int t = threadIdx.x;
    const int sub = t >> 7;        // 0/1: two nodes per block per iter
    const int f = t & 127;
    float acc = 0.f;
    for (int n = blockIdx.x * 2 + sub; n < NN; n += gridDim.x * 2) {
        float mean = zx[(size_t)n * 256 + f];
        float s    = zx[(size_t)n * 256 + 128 + f];
        float sp   = fmaxf(s, 0.f) + log1pf(expf(-fabsf(s)));
        float sd   = sp + 0.01f;
        float e    = eps[(size_t)n * 128 + f];
        float hv   = mean + sd * e;
        h[(size_t)n * 128 + f] = hv;
        acc += 0.5f * hv * hv - 0.5f * e * e - logf(sd);
    }
    #pragma unroll
    for (int o = 32; o > 0; o >>= 1) acc += __shfl_xor(acc, o);
    __shared__ float wsum[4];
    if ((t & 63) == 0) wsum[t >> 6] = acc;
    __syncthreads();
    if (t == 0)
        unsafeAtomicAdd(l2acc, (double)(wsum[0] + wsum[1] + wsum[2] + wsum[3]));
}

// log_softmax over rows of 40 (+ b1); 4 nodes per block (wave per node).
__global__ __launch_bounds__(256) void logsoftmax_k(
    const float* __restrict__ s3, const float* __restrict__ b1,
    float* __restrict__ out)
{
    int n = blockIdx.x * 4 + (threadIdx.x >> 6);
    int f = threadIdx.x & 63;
    float xv = 0.f, x = -1e30f;
    if (f < 40) { xv = s3[(size_t)n * 40 + f] + b1[f]; x = xv; }
    float m = x;
    #pragma unroll
    for (int o = 32; o > 0; o >>= 1) m = fmaxf(m, __shfl_xor(m, o));
    float ex = (f < 40) ? expf(xv - m) : 0.f;
    float ssum = ex;
    #pragma unroll
    for (int o = 32; o > 0; o >>= 1) ssum += __shfl_xor(ssum, o);
    if (f < 40) out[(size_t)n * 40 + f] = xv - m - logf(ssum);
}

__global__ void finalize_l2(const double* __restrict__ l2acc, float* __restrict__ out)
{
    if (threadIdx.x == 0 && blockIdx.x == 0)
        out[(size_t)NN * 40] = (float)(*l2acc / (double)NN);
}

// ---------------------------------------------------------------------------
extern "C" void kernel_launch(void* const* d_in, const int* in_sizes, int n_in,
                              void* d_out, int out_size, void* d_ws, size_t ws_size,
                              hipStream_t stream)
{
    const float* x    = (const float*)d_in[0];
    const int*   arow = (const int*)d_in[1];
    const int*   acol = (const int*)d_in[2];
    const float* aval = (const float*)d_in[3];
    const float* eps  = (const float*)d_in[4];
    const float* Wz1  = (const float*)d_in[5];
    const float* bz1  = (const float*)d_in[6];
    const float* Wz2  = (const float*)d_in[7];
    const float* bz2  = (const float*)d_in[8];
    const float* W0   = (const float*)d_in[9];
    const float* b0   = (const float*)d_in[10];
    const float* W1   = (const float*)d_in[11];
    const float* b1   = (const float*)d_in[12];
    float* out = (float*)d_out;
    const int E = in_sizes[1];

    float*  bufA  = (float*)d_ws;                       // N*256
    float*  bufB  = bufA + (size_t)NN * 256;            // N*256
    double* l2acc = (double*)(bufB + (size_t)NN * 256); // 1

    dim3 blk(256);
    const int gM = (NN + 63) / 64;  // 1563

    // G1: tmp1 = relu(x@Wz1 + bz1) -> bufB  (N x 128)
    gemm64<128, true, true><<<dim3(gM, 2), blk, 0, stream>>>(x, Wz1, bz1, bufB, NN, 128);
    // G2: feats = tmp1@Wz2 + bz2 -> bufA    (N x 256)
    gemm64<128, false, true><<<dim3(gM, 4), blk, 0, stream>>>(bufB, Wz2, bz2, bufA, NN, 256);

    // spmm1: z_x_hat = A * feats -> bufB
    hipMemsetAsync(bufB, 0, (size_t)NN * 256 * sizeof(float), stream);
    hipMemsetAsync(l2acc, 0, sizeof(double), stream);
    spmm_f256<<<dim3((E + 3) / 4), blk, 0, stream>>>(arow, acol, aval, bufA, bufB, E);

    // sampling: h -> bufA[0 : N*128], l2 partials
    sample_kernel<<<dim3(2048), blk, 0, stream>>>(bufB, eps, bufA, l2acc);

    // G3: hW0 = h @ W0 -> bufB (N x 256)
    gemm64<128, false, false><<<dim3(gM, 4), blk, 0, stream>>>(bufA, W0, nullptr, bufB, NN, 256);

    // spmm2: s2 = A * hW0 -> bufA
    hipMemsetAsync(bufA, 0, (size_t)NN * 256 * sizeof(float), stream);
    spmm_f256<<<dim3((E + 3) / 4), blk, 0, stream>>>(arow, acol, aval, bufB, bufA, E);

    // G4: hW1 = relu(s2 + b0) @ W1 -> bufB (N x 40)
    gemm_out40<<<dim3(NN / 32), blk, 0, stream>>>(bufA, b0, W1, bufB);

    // spmm3: s3 = A * hW1 -> bufA (N x 40)
    hipMemsetAsync(bufA, 0, (size_t)NN * 40 * sizeof(float), stream);
    spmm_f40<<<dim3((int)(((long long)E * 40 + 255) / 256)), blk, 0, stream>>>(arow, acol, aval, bufB, bufA, E);

    // out = log_softmax(s3 + b1); out[N*40] = l2
    logsoftmax_k<<<dim3(NN / 4), blk, 0, stream>>>(bufA, b1, out);
    finalize_l2<<<1, 64, 0, stream>>>(l2acc, out);
}

// Round 2
// 1232.158 us; speedup vs baseline: 9.2374x; 9.2374x over previous
//
#include <hip/hip_runtime.h>
#include <math.h>

constexpr int NN   = 100000;
constexpr int FIN  = 128;
constexpr int FHID = 256;
constexpr int FOUT = 40;

// ---------------------------------------------------------------------------
// Dense GEMM: C[M x NC] = act(A[M x 128] @ W[128 x NC] + bias), 64x64 tiles.
// ---------------------------------------------------------------------------
template<int K, bool RELU_OUT, bool HAS_BIAS>
__global__ __launch_bounds__(256) void gemm64(
    const float* __restrict__ A, const float* __restrict__ W,
    const float* __restrict__ bias, float* __restrict__ C, int M, int NC)
{
    __shared__ float As[64][K + 4];
    __shared__ float Wt[64][K + 4];
    const int t = threadIdx.x;
    const int brow = blockIdx.x * 64;
    const int bcol = blockIdx.y * 64;

    #pragma unroll
    for (int i = 0; i < (64 * K) / (256 * 4); ++i) {
        int idx = (t + i * 256) * 4;
        int r = idx / K, c = idx % K;
        int gr = brow + r;
        float4 v = make_float4(0.f, 0.f, 0.f, 0.f);
        if (gr < M) v = *reinterpret_cast<const float4*>(&A[(size_t)gr * K + c]);
        *reinterpret_cast<float4*>(&As[r][c]) = v;
    }
    #pragma unroll
    for (int i = 0; i < (64 * K) / (256 * 4); ++i) {
        int idx = (t + i * 256) * 4;
        int k = idx / 64, c = idx % 64;
        float4 v = *reinterpret_cast<const float4*>(&W[(size_t)k * NC + bcol + c]);
        Wt[c + 0][k] = v.x; Wt[c + 1][k] = v.y; Wt[c + 2][k] = v.z; Wt[c + 3][k] = v.w;
    }
    __syncthreads();

    const int tx = t & 15, ty = t >> 4;
    float acc[4][4] = {};
    for (int k = 0; k < K; k += 4) {
        float4 a4[4], b4[4];
        #pragma unroll
        for (int i = 0; i < 4; ++i) a4[i] = *reinterpret_cast<const float4*>(&As[ty + 16 * i][k]);
        #pragma unroll
        for (int j = 0; j < 4; ++j) b4[j] = *reinterpret_cast<const float4*>(&Wt[tx + 16 * j][k]);
        #pragma unroll
        for (int i = 0; i < 4; ++i)
            #pragma unroll
            for (int j = 0; j < 4; ++j) {
                acc[i][j] += a4[i].x * b4[j].x;
                acc[i][j] += a4[i].y * b4[j].y;
                acc[i][j] += a4[i].z * b4[j].z;
                acc[i][j] += a4[i].w * b4[j].w;
            }
    }

    #pragma unroll
    for (int i = 0; i < 4; ++i) {
        int gr = brow + ty + 16 * i;
        if (gr >= M) continue;
        #pragma unroll
        for (int j = 0; j < 4; ++j) {
            int gc = bcol + tx + 16 * j;
            float v = acc[i][j];
            if (HAS_BIAS) v += bias[gc];
            if (RELU_OUT) v = fmaxf(v, 0.f);
            C[(size_t)gr * NC + gc] = v;
        }
    }
}

// ---------------------------------------------------------------------------
// Final GEMM: C[M x 40] = relu(A[M x 256] + b0) @ W1[256 x 40]
// ---------------------------------------------------------------------------
__global__ __launch_bounds__(256) void gemm_out40(
    const float* __restrict__ A, const float* __restrict__ b0,
    const float* __restrict__ W1, float* __restrict__ C)
{
    __shared__ float As[32][260];
    __shared__ float Wt[40][260];
    const int t = threadIdx.x;
    const int brow = blockIdx.x * 32;

    #pragma unroll
    for (int i = 0; i < 8; ++i) {
        int idx = (t + i * 256) * 4;
        int r = idx >> 8, c = idx & 255;
        float4 v = *reinterpret_cast<const float4*>(&A[(size_t)(brow + r) * 256 + c]);
        v.x = fmaxf(v.x + b0[c + 0], 0.f);
        v.y = fmaxf(v.y + b0[c + 1], 0.f);
        v.z = fmaxf(v.z + b0[c + 2], 0.f);
        v.w = fmaxf(v.w + b0[c + 3], 0.f);
        *reinterpret_cast<float4*>(&As[r][c]) = v;
    }
    #pragma unroll
    for (int i = 0; i < 10; ++i) {
        int idx = (t + i * 256) * 4;
        int k = idx / 40, c = idx % 40;
        float4 v = *reinterpret_cast<const float4*>(&W1[idx]);
        Wt[c + 0][k] = v.x; Wt[c + 1][k] = v.y; Wt[c + 2][k] = v.z; Wt[c + 3][k] = v.w;
    }
    __syncthreads();

    const int tx = t & 7, ty = t >> 3;
    float acc[5] = {};
    for (int k = 0; k < 256; k += 4) {
        float4 a = *reinterpret_cast<const float4*>(&As[ty][k]);
        #pragma unroll
        for (int j = 0; j < 5; ++j) {
            float4 b = *reinterpret_cast<const float4*>(&Wt[tx + 8 * j][k]);
            acc[j] += a.x * b.x + a.y * b.y + a.z * b.z + a.w * b.w;
        }
    }
    const int gr = brow + ty;
    #pragma unroll
    for (int j = 0; j < 5; ++j)
        C[(size_t)gr * 40 + tx + 8 * j] = acc[j];
}

// ---------------------------------------------------------------------------
// CSR build: histogram -> 3-phase exclusive scan -> counting-sort scatter.
// ---------------------------------------------------------------------------
__global__ __launch_bounds__(256) void hist_k(
    const int* __restrict__ row, int* __restrict__ cnt, int E)
{
    int e = blockIdx.x * 256 + threadIdx.x;
    if (e < E) atomicAdd(&cnt[row[e]], 1);
}

// 1024 elements per block: per-thread 4-seq + wave shfl scan + cross-wave.
__global__ __launch_bounds__(256) void scan_blk(
    const int* __restrict__ cnt, int* __restrict__ rp, int* __restrict__ bsums, int n)
{
    const int t = threadIdx.x;
    const int lane = t & 63, wid = t >> 6;
    const int base = blockIdx.x * 1024 + t * 4;
    int a0 = 0, a1 = 0, a2 = 0, a3 = 0;
    if (base + 3 < n) {
        int4 v = *reinterpret_cast<const int4*>(&cnt[base]);
        a0 = v.x; a1 = v.y; a2 = v.z; a3 = v.w;
    } else {
        if (base + 0 < n) a0 = cnt[base + 0];
        if (base + 1 < n) a1 = cnt[base + 1];
        if (base + 2 < n) a2 = cnt[base + 2];
        if (base + 3 < n) a3 = cnt[base + 3];
    }
    int s0 = a0, s1 = s0 + a1, s2 = s1 + a2, s3 = s2 + a3;  // local inclusive
    int v = s3;
    #pragma unroll
    for (int o = 1; o < 64; o <<= 1) {
        int u = __shfl_up(v, o);
        if (lane >= o) v += u;
    }
    __shared__ int wtot[4];
    if (lane == 63) wtot[wid] = v;
    __syncthreads();
    int woff = 0;
    #pragma unroll
    for (int w = 0; w < 4; ++w) if (w < wid) woff += wtot[w];
    int texcl = woff + v - s3;  // exclusive prefix of this thread's chunk
    if (base + 0 < n) rp[base + 0] = texcl;
    if (base + 1 < n) rp[base + 1] = texcl + s0;
    if (base + 2 < n) rp[base + 2] = texcl + s1;
    if (base + 3 < n) rp[base + 3] = texcl + s2;
    if (t == 255) bsums[blockIdx.x] = woff + v;  // block total
}

__global__ void scan_mid(const int* __restrict__ bsums, int* __restrict__ boff, int nb)
{
    if (threadIdx.x == 0 && blockIdx.x == 0) {
        int run = 0;
        for (int b = 0; b < nb; ++b) { boff[b] = run; run += bsums[b]; }
    }
}

__global__ __launch_bounds__(256) void scan_add(
    int* __restrict__ rp, const int* __restrict__ boff, int n, int E)
{
    int i = blockIdx.x * 256 + threadIdx.x;
    if (i < n) rp[i] += boff[i >> 10];
    if (i == 0) rp[n] = E;
}

__global__ __launch_bounds__(256) void scatter_k(
    const int* __restrict__ row, const int* __restrict__ col,
    const float* __restrict__ val, const int* __restrict__ rp,
    int* __restrict__ cnt, int2* __restrict__ edges, int E)
{
    int e = blockIdx.x * 256 + threadIdx.x;
    if (e >= E) return;
    int r = row[e];
    int p = rp[r] + atomicAdd(&cnt[r], 1);
    edges[p] = make_int2(col[e], __float_as_int(val[e]));
}

// ---------------------------------------------------------------------------
// CSR SpMM gather F=256, fused with sampling + l2 partial (spmm1).
// One wave per row; lane holds float4 of the 256-wide accumulator.
// ---------------------------------------------------------------------------
__global__ __launch_bounds__(256) void spmm256_sample(
    const int* __restrict__ rp, const int2* __restrict__ edges,
    const float* __restrict__ mat, const float* __restrict__ eps,
    float* __restrict__ hout, float* __restrict__ partials)
{
    const int r = (int)((blockIdx.x * 256 + threadIdx.x) >> 6);
    const int lane = threadIdx.x & 63;
    float4 acc = make_float4(0.f, 0.f, 0.f, 0.f);
    if (r < NN) {
        const int beg = rp[r], end = rp[r + 1];
        for (int e = beg; e < end; ++e) {
            int2 cv = edges[e];
            float v = __int_as_float(cv.y);
            float4 f = reinterpret_cast<const float4*>(mat + (size_t)cv.x * 256)[lane];
            acc.x += v * f.x; acc.y += v * f.y; acc.z += v * f.z; acc.w += v * f.w;
        }
    }
    // lanes 0..31 hold mean[4l..4l+3]; lanes 32..63 hold s[4l..4l+3]
    const int src = (lane + 32) & 63;
    float sv0 = __shfl(acc.x, src);
    float sv1 = __shfl(acc.y, src);
    float sv2 = __shfl(acc.z, src);
    float sv3 = __shfl(acc.w, src);
    float p_l2 = 0.f;
    if (r < NN && lane < 32) {
        float4 e4 = reinterpret_cast<const float4*>(eps + (size_t)r * 128)[lane];
        float mn[4] = {acc.x, acc.y, acc.z, acc.w};
        float sv[4] = {sv0, sv1, sv2, sv3};
        float ev[4] = {e4.x, e4.y, e4.z, e4.w};
        float4 hv;
        float* hp = &hv.x;
        #pragma unroll
        for (int j = 0; j < 4; ++j) {
            float s  = sv[j];
            float sp = fmaxf(s, 0.f) + log1pf(expf(-fabsf(s)));
            float sd = sp + 0.01f;
            float h  = mn[j] + sd * ev[j];
            hp[j] = h;
            p_l2 += 0.5f * h * h - 0.5f * ev[j] * ev[j] - logf(sd);
        }
        reinterpret_cast<float4*>(hout + (size_t)r * 128)[lane] = hv;
    }
    #pragma unroll
    for (int o = 32; o > 0; o >>= 1) p_l2 += __shfl_xor(p_l2, o);
    __shared__ float ws[4];
    if (lane == 0) ws[threadIdx.x >> 6] = p_l2;
    __syncthreads();
    if (threadIdx.x == 0) partials[blockIdx.x] = ws[0] + ws[1] + ws[2] + ws[3];
}

// CSR SpMM gather F=256, plain (spmm2).
__global__ __launch_bounds__(256) void spmm256_plain(
    const int* __restrict__ rp, const int2* __restrict__ edges,
    const float* __restrict__ mat, float* __restrict__ out)
{
    const int r = (int)((blockIdx.x * 256 + threadIdx.x) >> 6);
    const int lane = threadIdx.x & 63;
    if (r >= NN) return;
    const int beg = rp[r], end = rp[r + 1];
    float4 acc = make_float4(0.f, 0.f, 0.f, 0.f);
    for (int e = beg; e < end; ++e) {
        int2 cv = edges[e];
        float v = __int_as_float(cv.y);
        float4 f = reinterpret_cast<const float4*>(mat + (size_t)cv.x * 256)[lane];
        acc.x += v * f.x; acc.y += v * f.y; acc.z += v * f.z; acc.w += v * f.w;
    }
    reinterpret_cast<float4*>(out + (size_t)r * 256)[lane] = acc;
}

// CSR SpMM gather F=40 fused with +b1 and log_softmax (spmm3) -> d_out.
__global__ __launch_bounds__(256) void spmm40_lsm(
    const int* __restrict__ rp, const int2* __restrict__ edges,
    const float* __restrict__ mat, const float* __restrict__ b1,
    float* __restrict__ out)
{
    const int r = (int)((blockIdx.x * 256 + threadIdx.x) >> 6);
    const int lane = threadIdx.x & 63;
    if (r >= NN) return;
    const int beg = rp[r], end = rp[r + 1];
    float acc = 0.f;
    for (int e = beg; e < end; ++e) {
        int2 cv = edges[e];
        if (lane < 40) acc += __int_as_float(cv.y) * mat[(size_t)cv.x * 40 + lane];
    }
    float xv = (lane < 40) ? acc + b1[lane] : -1e30f;
    float m = xv;
    #pragma unroll
    for (int o = 32; o > 0; o >>= 1) m = fmaxf(m, __shfl_xor(m, o));
    float ex = (lane < 40) ? expf(xv - m) : 0.f;
    float ssum = ex;
    #pragma unroll
    for (int o = 32; o > 0; o >>= 1) ssum += __shfl_xor(ssum, o);
    if (lane < 40) out[(size_t)r * 40 + lane] = xv - m - logf(ssum);
}

__global__ __launch_bounds__(256) void finalize_l2(
    const float* __restrict__ partials, int np, float* __restrict__ out)
{
    double a = 0.0;
    for (int i = threadIdx.x; i < np; i += 256) a += (double)partials[i];
    #pragma unroll
    for (int o = 32; o > 0; o >>= 1) a += __shfl_xor(a, o);
    __shared__ double ws[4];
    if ((threadIdx.x & 63) == 0) ws[threadIdx.x >> 6] = a;
    __syncthreads();
    if (threadIdx.x == 0)
        out[(size_t)NN * 40] = (float)((ws[0] + ws[1] + ws[2] + ws[3]) / (double)NN);
}

// ---------------------------------------------------------------------------
extern "C" void kernel_launch(void* const* d_in, const int* in_sizes, int n_in,
                              void* d_out, int out_size, void* d_ws, size_t ws_size,
                              hipStream_t stream)
{
    const float* x    = (const float*)d_in[0];
    const int*   arow = (const int*)d_in[1];
    const int*   acol = (const int*)d_in[2];
    const float* aval = (const float*)d_in[3];
    const float* eps  = (const float*)d_in[4];
    const float* Wz1  = (const float*)d_in[5];
    const float* bz1  = (const float*)d_in[6];
    const float* Wz2  = (const float*)d_in[7];
    const float* bz2  = (const float*)d_in[8];
    const float* W0   = (const float*)d_in[9];
    const float* b0   = (const float*)d_in[10];
    const float* W1   = (const float*)d_in[11];
    const float* b1   = (const float*)d_in[12];
    float* out = (float*)d_out;
    const int E = in_sizes[1];

    // workspace layout (16B-aligned sections)
    float* bufA = (float*)d_ws;                    // N*256
    float* bufB = bufA + (size_t)NN * 256;         // N*256
    int*   rp    = (int*)(bufB + (size_t)NN * 256); // N+1 (padded to 100004)
    int*   cnt   = rp + 100004;                     // N
    int*   bsums = cnt + NN;                        // 128
    int*   boff  = bsums + 128;                     // 128
    float* partials = (float*)(boff + 128);         // 25000 (padded to 25004)
    int2*  edges = (int2*)(partials + 25004);       // E

    dim3 blk(256);
    const int gM = (NN + 63) / 64;       // 1563
    const int gE = (E + 255) / 256;      // 6250
    const int nScan = (NN + 1023) / 1024; // 98
    const int gRow = (NN * 64) / 256;     // 25000 (one wave per row)

    // --- CSR build ---
    hipMemsetAsync(cnt, 0, (size_t)NN * sizeof(int), stream);
    hist_k<<<dim3(gE), blk, 0, stream>>>(arow, cnt, E);
    scan_blk<<<dim3(nScan), blk, 0, stream>>>(cnt, rp, bsums, NN);
    scan_mid<<<dim3(1), dim3(64), 0, stream>>>(bsums, boff, nScan);
    scan_add<<<dim3((NN + 256) / 256), blk, 0, stream>>>(rp, boff, NN, E);
    hipMemsetAsync(cnt, 0, (size_t)NN * sizeof(int), stream);
    scatter_k<<<dim3(gE), blk, 0, stream>>>(arow, acol, aval, rp, cnt, edges, E);

    // --- dense + graph pipeline ---
    // G1: t1 = relu(x@Wz1 + bz1) -> bufB (N x 128)
    gemm64<128, true, true><<<dim3(gM, 2), blk, 0, stream>>>(x, Wz1, bz1, bufB, NN, 128);
    // G2: feats = t1@Wz2 + bz2 -> bufA (N x 256)
    gemm64<128, false, true><<<dim3(gM, 4), blk, 0, stream>>>(bufB, Wz2, bz2, bufA, NN, 256);
    // spmm1 (+sample fused): feats -> h in bufB (N x 128), l2 partials
    spmm256_sample<<<dim3(gRow), blk, 0, stream>>>(rp, edges, bufA, eps, bufB, partials);
    // G3: s = h @ W0 -> bufA (N x 256)
    gemm64<128, false, false><<<dim3(gM, 4), blk, 0, stream>>>(bufB, W0, nullptr, bufA, NN, 256);
    // spmm2: s2 = A * s -> bufB (N x 256)
    spmm256_plain<<<dim3(gRow), blk, 0, stream>>>(rp, edges, bufA, bufB);
    // G4: g4 = relu(s2 + b0) @ W1 -> bufA (N x 40)
    gemm_out40<<<dim3(NN / 32), blk, 0, stream>>>(bufB, b0, W1, bufA);
    // spmm3 (+b1 + log_softmax fused) -> out
    spmm40_lsm<<<dim3(gRow), blk, 0, stream>>>(rp, edges, bufA, b1, out);
    // l2 scalar
    finalize_l2<<<dim3(1), blk, 0, stream>>>(partials, gRow, out);
}

// Round 3
// 936.717 us; speedup vs baseline: 12.1509x; 1.3154x over previous
//
#include <hip/hip_runtime.h>
#include <math.h>

constexpr int NN   = 100000;

using f32x4  = __attribute__((ext_vector_type(4))) float;
using s16x8  = __attribute__((ext_vector_type(8))) short;

__device__ __forceinline__ unsigned short f2bf(float f) {
    unsigned u = __float_as_uint(f);
    unsigned r = u + 0x7FFFu + ((u >> 16) & 1u);
    return (unsigned short)(r >> 16);
}
__device__ __forceinline__ float bf2f(unsigned short u) {
    return __uint_as_float(((unsigned)u) << 16);
}

// ---------------------------------------------------------------------------
// Pack weight W[K x NC] (fp32) into MFMA B-fragment order, bf16, zero-padded
// to NCpad cols. Layout: Wf[((ncg*KK + kk)*64 + lane)*8 + j] =
//   bf16( W[kk*32 + 8*(lane>>4) + j][ncg*16 + (lane&15)] )
// ---------------------------------------------------------------------------
__global__ __launch_bounds__(256) void wfrag_k(
    const float* __restrict__ W, short* __restrict__ Wf, int K, int NC, int NCpad)
{
    const int KK = K / 32;
    int total = (NCpad / 16) * KK * 64;
    int tid = blockIdx.x * 256 + threadIdx.x;
    if (tid >= total) return;
    int lane = tid & 63, f = tid >> 6;
    int ncg = f / KK, kk = f % KK;
    int col = ncg * 16 + (lane & 15);
    int k0  = kk * 32 + 8 * (lane >> 4);
    s16x8 o;
    #pragma unroll
    for (int j = 0; j < 8; ++j)
        o[j] = (col < NC) ? (short)f2bf(W[(size_t)(k0 + j) * NC + col]) : (short)0;
    *reinterpret_cast<s16x8*>(Wf + (size_t)tid * 8) = o;
}

// ---------------------------------------------------------------------------
// MFMA GEMM: C[M x NCout] = act(A[M x K] @ W + bias)
// AK: 0 = A fp32 row-major, 1 = A bf16 row-major, 2 = A bf16 + relu(a + b0[k])
// Wave computes 64 x (CB*16); block = WM*WN waves.
// ---------------------------------------------------------------------------
template<int K, int WM, int WN, int CB, int AK, bool OBF16, bool HASBIAS, bool ORELU>
__global__ __launch_bounds__(WM * WN * 64) void gemm_mfma(
    const void* __restrict__ Ain, const short* __restrict__ Wf,
    const float* __restrict__ bias, const float* __restrict__ b0,
    void* __restrict__ Cout, int M, int NCout)
{
    constexpr int KK = K / 32;
    const int tid = threadIdx.x;
    const int lane = tid & 63, wid = tid >> 6;
    const int wm = wid % WM, wn = wid / WM;
    const int rowBase = blockIdx.x * (WM * 64) + wm * 64;
    const int cfb = wn * CB;       // col-frag base (16-col units)
    const int l15 = lane & 15, lh = lane >> 4;

    f32x4 acc[4][CB];
    #pragma unroll
    for (int i = 0; i < 4; ++i)
        #pragma unroll
        for (int j = 0; j < CB; ++j) acc[i][j] = (f32x4)0.f;

    #pragma unroll
    for (int kk = 0; kk < KK; ++kk) {
        const int k0 = kk * 32 + lh * 8;
        s16x8 a[4];
        #pragma unroll
        for (int rb = 0; rb < 4; ++rb) {
            int row = rowBase + rb * 16 + l15;
            row = row < M ? row : M - 1;
            if (AK == 0) {
                const float* ap = (const float*)Ain + (size_t)row * K + k0;
                float4 u = *reinterpret_cast<const float4*>(ap);
                float4 v = *reinterpret_cast<const float4*>(ap + 4);
                a[rb][0] = (short)f2bf(u.x); a[rb][1] = (short)f2bf(u.y);
                a[rb][2] = (short)f2bf(u.z); a[rb][3] = (short)f2bf(u.w);
                a[rb][4] = (short)f2bf(v.x); a[rb][5] = (short)f2bf(v.y);
                a[rb][6] = (short)f2bf(v.z); a[rb][7] = (short)f2bf(v.w);
            } else if (AK == 1) {
                a[rb] = *reinterpret_cast<const s16x8*>((const short*)Ain + (size_t)row * K + k0);
            } else {
                s16x8 s = *reinterpret_cast<const s16x8*>((const short*)Ain + (size_t)row * K + k0);
                float4 ba = *reinterpret_cast<const float4*>(b0 + k0);
                float4 bb = *reinterpret_cast<const float4*>(b0 + k0 + 4);
                float bv[8] = {ba.x, ba.y, ba.z, ba.w, bb.x, bb.y, bb.z, bb.w};
                #pragma unroll
                for (int j = 0; j < 8; ++j) {
                    float fv = bf2f((unsigned short)s[j]) + bv[j];
                    a[rb][j] = (short)f2bf(fmaxf(fv, 0.f));
                }
            }
        }
        s16x8 b[CB];
        #pragma unroll
        for (int cb = 0; cb < CB; ++cb)
            b[cb] = *reinterpret_cast<const s16x8*>(
                Wf + ((size_t)((cfb + cb) * KK + kk) * 64 + lane) * 8);
        #pragma unroll
        for (int rb = 0; rb < 4; ++rb)
            #pragma unroll
            for (int cb = 0; cb < CB; ++cb)
                acc[rb][cb] = __builtin_amdgcn_mfma_f32_16x16x32_bf16(
                    a[rb], b[cb], acc[rb][cb], 0, 0, 0);
    }

    #pragma unroll
    for (int cb = 0; cb < CB; ++cb) {
        int col = (cfb + cb) * 16 + l15;
        float bs = HASBIAS ? bias[col] : 0.f;
        #pragma unroll
        for (int rb = 0; rb < 4; ++rb) {
            #pragma unroll
            for (int r = 0; r < 4; ++r) {
                int row = rowBase + rb * 16 + lh * 4 + r;
                if (row >= M) continue;
                float v = acc[rb][cb][r] + bs;
                if (ORELU) v = fmaxf(v, 0.f);
                if (OBF16)
                    ((unsigned short*)Cout)[(size_t)row * NCout + col] = f2bf(v);
                else
                    ((float*)Cout)[(size_t)row * NCout + col] = v;
            }
        }
    }
}

// ---------------------------------------------------------------------------
// CSR build: histogram -> 3-phase exclusive scan -> counting-sort scatter.
// ---------------------------------------------------------------------------
__global__ __launch_bounds__(256) void hist_k(
    const int* __restrict__ row, int* __restrict__ cnt, int E)
{
    int e = blockIdx.x * 256 + threadIdx.x;
    if (e < E) atomicAdd(&cnt[row[e]], 1);
}

__global__ __launch_bounds__(256) void scan_blk(
    const int* __restrict__ cnt, int* __restrict__ rp, int* __restrict__ bsums, int n)
{
    const int t = threadIdx.x;
    const int lane = t & 63, wid = t >> 6;
    const int base = blockIdx.x * 1024 + t * 4;
    int a0 = 0, a1 = 0, a2 = 0, a3 = 0;
    if (base + 3 < n) {
        int4 v = *reinterpret_cast<const int4*>(&cnt[base]);
        a0 = v.x; a1 = v.y; a2 = v.z; a3 = v.w;
    } else {
        if (base + 0 < n) a0 = cnt[base + 0];
        if (base + 1 < n) a1 = cnt[base + 1];
        if (base + 2 < n) a2 = cnt[base + 2];
        if (base + 3 < n) a3 = cnt[base + 3];
    }
    int s0 = a0, s1 = s0 + a1, s2 = s1 + a2, s3 = s2 + a3;
    int v = s3;
    #pragma unroll
    for (int o = 1; o < 64; o <<= 1) {
        int u = __shfl_up(v, o);
        if (lane >= o) v += u;
    }
    __shared__ int wtot[4];
    if (lane == 63) wtot[wid] = v;
    __syncthreads();
    int woff = 0;
    #pragma unroll
    for (int w = 0; w < 4; ++w) if (w < wid) woff += wtot[w];
    int texcl = woff + v - s3;
    if (base + 0 < n) rp[base + 0] = texcl;
    if (base + 1 < n) rp[base + 1] = texcl + s0;
    if (base + 2 < n) rp[base + 2] = texcl + s1;
    if (base + 3 < n) rp[base + 3] = texcl + s2;
    if (t == 255) bsums[blockIdx.x] = woff + v;
}

__global__ void scan_mid(const int* __restrict__ bsums, int* __restrict__ boff, int nb)
{
    if (threadIdx.x == 0 && blockIdx.x == 0) {
        int run = 0;
        for (int b = 0; b < nb; ++b) { boff[b] = run; run += bsums[b]; }
    }
}

__global__ __launch_bounds__(256) void scan_add(
    int* __restrict__ rp, const int* __restrict__ boff, int n, int E)
{
    int i = blockIdx.x * 256 + threadIdx.x;
    if (i < n) rp[i] += boff[i >> 10];
    if (i == 0) rp[n] = E;
}

__global__ __launch_bounds__(256) void scatter_k(
    const int* __restrict__ row, const int* __restrict__ col,
    const float* __restrict__ val, const int* __restrict__ rp,
    int* __restrict__ cnt, int2* __restrict__ edges, int E)
{
    int e = blockIdx.x * 256 + threadIdx.x;
    if (e >= E) return;
    int r = row[e];
    int p = rp[r] + atomicAdd(&cnt[r], 1);
    edges[p] = make_int2(col[e], __float_as_int(val[e]));
}

// ---------------------------------------------------------------------------
// CSR SpMM gather F=256 over bf16 mat, fused with sampling + l2 (spmm1).
// One wave per row; lane owns 4 consecutive features.
// ---------------------------------------------------------------------------
__global__ __launch_bounds__(256) void spmm256_sample(
    const int* __restrict__ rp, const int2* __restrict__ edges,
    const unsigned short* __restrict__ mat, const float* __restrict__ eps,
    unsigned short* __restrict__ hout, float* __restrict__ partials)
{
    const int r = (int)((blockIdx.x * 256 + threadIdx.x) >> 6);
    const int lane = threadIdx.x & 63;
    float4 acc = make_float4(0.f, 0.f, 0.f, 0.f);
    if (r < NN) {
        const int beg = rp[r], end = rp[r + 1];
        for (int e = beg; e < end; ++e) {
            int2 cv = edges[e];
            float v = __int_as_float(cv.y);
            ushort4 f = reinterpret_cast<const ushort4*>(mat + (size_t)cv.x * 256)[lane];
            acc.x += v * bf2f(f.x); acc.y += v * bf2f(f.y);
            acc.z += v * bf2f(f.z); acc.w += v * bf2f(f.w);
        }
    }
    const int src = (lane + 32) & 63;
    float sv0 = __shfl(acc.x, src);
    float sv1 = __shfl(acc.y, src);
    float sv2 = __shfl(acc.z, src);
    float sv3 = __shfl(acc.w, src);
    float p_l2 = 0.f;
    if (r < NN && lane < 32) {
        float4 e4 = reinterpret_cast<const float4*>(eps + (size_t)r * 128)[lane];
        float mn[4] = {acc.x, acc.y, acc.z, acc.w};
        float sv[4] = {sv0, sv1, sv2, sv3};
        float ev[4] = {e4.x, e4.y, e4.z, e4.w};
        ushort4 hv;
        unsigned short* hp = &hv.x;
        #pragma unroll
        for (int j = 0; j < 4; ++j) {
            float s  = sv[j];
            float sp = fmaxf(s, 0.f) + log1pf(expf(-fabsf(s)));
            float sd = sp + 0.01f;
            float h  = mn[j] + sd * ev[j];
            hp[j] = f2bf(h);
            p_l2 += 0.5f * h * h - 0.5f * ev[j] * ev[j] - logf(sd);
        }
        reinterpret_cast<ushort4*>(hout + (size_t)r * 128)[lane] = hv;
    }
    #pragma unroll
    for (int o = 32; o > 0; o >>= 1) p_l2 += __shfl_xor(p_l2, o);
    __shared__ float ws[4];
    if (lane == 0) ws[threadIdx.x >> 6] = p_l2;
    __syncthreads();
    if (threadIdx.x == 0) partials[blockIdx.x] = ws[0] + ws[1] + ws[2] + ws[3];
}

// CSR SpMM gather F=256 bf16 in -> bf16 out (spmm2).
__global__ __launch_bounds__(256) void spmm256_plain(
    const int* __restrict__ rp, const int2* __restrict__ edges,
    const unsigned short* __restrict__ mat, unsigned short* __restrict__ out)
{
    const int r = (int)((blockIdx.x * 256 + threadIdx.x) >> 6);
    const int lane = threadIdx.x & 63;
    if (r >= NN) return;
    const int beg = rp[r], end = rp[r + 1];
    float4 acc = make_float4(0.f, 0.f, 0.f, 0.f);
    for (int e = beg; e < end; ++e) {
        int2 cv = edges[e];
        float v = __int_as_float(cv.y);
        ushort4 f = reinterpret_cast<const ushort4*>(mat + (size_t)cv.x * 256)[lane];
        acc.x += v * bf2f(f.x); acc.y += v * bf2f(f.y);
        acc.z += v * bf2f(f.z); acc.w += v * bf2f(f.w);
    }
    ushort4 o;
    o.x = f2bf(acc.x); o.y = f2bf(acc.y); o.z = f2bf(acc.z); o.w = f2bf(acc.w);
    reinterpret_cast<ushort4*>(out + (size_t)r * 256)[lane] = o;
}

// CSR SpMM gather F=40 (fp32 mat, stride 48) + b1 + log_softmax -> d_out.
__global__ __launch_bounds__(256) void spmm40_lsm(
    const int* __restrict__ rp, const int2* __restrict__ edges,
    const float* __restrict__ mat, const float* __restrict__ b1,
    float* __restrict__ out)
{
    const int r = (int)((blockIdx.x * 256 + threadIdx.x) >> 6);
    const int lane = threadIdx.x & 63;
    if (r >= NN) return;
    const int beg = rp[r], end = rp[r + 1];
    float acc = 0.f;
    for (int e = beg; e < end; ++e) {
        int2 cv = edges[e];
        if (lane < 40) acc += __int_as_float(cv.y) * mat[(size_t)cv.x * 48 + lane];
    }
    float xv = (lane < 40) ? acc + b1[lane] : -1e30f;
    float m = xv;
    #pragma unroll
    for (int o = 32; o > 0; o >>= 1) m = fmaxf(m, __shfl_xor(m, o));
    float ex = (lane < 40) ? expf(xv - m) : 0.f;
    float ssum = ex;
    #pragma unroll
    for (int o = 32; o > 0; o >>= 1) ssum += __shfl_xor(ssum, o);
    if (lane < 40) out[(size_t)r * 40 + lane] = xv - m - logf(ssum);
}

__global__ __launch_bounds__(256) void finalize_l2(
    const float* __restrict__ partials, int np, float* __restrict__ out)
{
    double a = 0.0;
    for (int i = threadIdx.x; i < np; i += 256) a += (double)partials[i];
    #pragma unroll
    for (int o = 32; o > 0; o >>= 1) a += __shfl_xor(a, o);
    __shared__ double ws[4];
    if ((threadIdx.x & 63) == 0) ws[threadIdx.x >> 6] = a;
    __syncthreads();
    if (threadIdx.x == 0)
        out[(size_t)NN * 40] = (float)((ws[0] + ws[1] + ws[2] + ws[3]) / (double)NN);
}

// ---------------------------------------------------------------------------
extern "C" void kernel_launch(void* const* d_in, const int* in_sizes, int n_in,
                              void* d_out, int out_size, void* d_ws, size_t ws_size,
                              hipStream_t stream)
{
    const float* x    = (const float*)d_in[0];
    const int*   arow = (const int*)d_in[1];
    const int*   acol = (const int*)d_in[2];
    const float* aval = (const float*)d_in[3];
    const float* eps  = (const float*)d_in[4];
    const float* Wz1  = (const float*)d_in[5];
    const float* bz1  = (const float*)d_in[6];
    const float* Wz2  = (const float*)d_in[7];
    const float* bz2  = (const float*)d_in[8];
    const float* W0   = (const float*)d_in[9];
    const float* b0   = (const float*)d_in[10];
    const float* W1   = (const float*)d_in[11];
    const float* b1   = (const float*)d_in[12];
    float* out = (float*)d_out;
    const int E = in_sizes[1];

    // ---- workspace bump allocation (16B aligned) ----
    char* p = (char*)d_ws;
    auto alloc = [&](size_t bytes) {
        char* q = p;
        p += (bytes + 15) & ~(size_t)15;
        return (void*)q;
    };
    int2* edges            = (int2*)alloc((size_t)E * 8);
    int*  rp               = (int*)alloc((size_t)(NN + 4) * 4);
    int*  cnt              = (int*)alloc((size_t)NN * 4);
    int*  bsums            = (int*)alloc(128 * 4);
    int*  boff             = (int*)alloc(128 * 4);
    float* partials        = (float*)alloc(25000 * 4);
    unsigned short* t1     = (unsigned short*)alloc((size_t)NN * 128 * 2);
    unsigned short* feats  = (unsigned short*)alloc((size_t)NN * 256 * 2);
    unsigned short* hbuf   = (unsigned short*)alloc((size_t)NN * 128 * 2);
    unsigned short* sg3    = (unsigned short*)alloc((size_t)NN * 256 * 2);
    unsigned short* s2     = (unsigned short*)alloc((size_t)NN * 256 * 2);
    float* g4              = (float*)alloc((size_t)NN * 48 * 4);
    short* wz1f            = (short*)alloc(8  * 4 * 64 * 8 * 2);
    short* wz2f            = (short*)alloc(16 * 4 * 64 * 8 * 2);
    short* w0f             = (short*)alloc(16 * 4 * 64 * 8 * 2);
    short* w1f             = (short*)alloc(3  * 8 * 64 * 8 * 2);

    dim3 blk(256);
    const int gE = (E + 255) / 256;
    const int nScan = (NN + 1023) / 1024;
    const int gRow = (NN * 64) / 256;   // wave per row

    // --- weight fragment packing ---
    wfrag_k<<<dim3((8  * 4 * 64 + 255) / 256), blk, 0, stream>>>(Wz1, wz1f, 128, 128, 128);
    wfrag_k<<<dim3((16 * 4 * 64 + 255) / 256), blk, 0, stream>>>(Wz2, wz2f, 128, 256, 256);
    wfrag_k<<<dim3((16 * 4 * 64 + 255) / 256), blk, 0, stream>>>(W0,  w0f,  128, 256, 256);
    wfrag_k<<<dim3((3  * 8 * 64 + 255) / 256), blk, 0, stream>>>(W1,  w1f,  256, 40, 48);

    // --- CSR build ---
    hipMemsetAsync(cnt, 0, (size_t)NN * sizeof(int), stream);
    hist_k<<<dim3(gE), blk, 0, stream>>>(arow, cnt, E);
    scan_blk<<<dim3(nScan), blk, 0, stream>>>(cnt, rp, bsums, NN);
    scan_mid<<<dim3(1), dim3(64), 0, stream>>>(bsums, boff, nScan);
    scan_add<<<dim3((NN + 256) / 256), blk, 0, stream>>>(rp, boff, NN, E);
    hipMemsetAsync(cnt, 0, (size_t)NN * sizeof(int), stream);
    scatter_k<<<dim3(gE), blk, 0, stream>>>(arow, acol, aval, rp, cnt, edges, E);

    // --- pipeline ---
    // G1: t1 = relu(x@Wz1 + bz1)    [AK=0 fp32 A] -> bf16 (N x 128)
    gemm_mfma<128, 2, 2, 4, 0, true, true, true><<<dim3(782), blk, 0, stream>>>(
        x, wz1f, bz1, nullptr, t1, NN, 128);
    // G2: feats = t1@Wz2 + bz2      [AK=1] -> bf16 (N x 256)
    gemm_mfma<128, 1, 4, 4, 1, true, true, false><<<dim3(1563), blk, 0, stream>>>(
        t1, wz2f, bz2, nullptr, feats, NN, 256);
    // spmm1 + sample: h -> bf16 (N x 128), l2 partials
    spmm256_sample<<<dim3(gRow), blk, 0, stream>>>(rp, edges, feats, eps, hbuf, partials);
    // G3: sg3 = h@W0                [AK=1] -> bf16 (N x 256)
    gemm_mfma<128, 1, 4, 4, 1, true, false, false><<<dim3(1563), blk, 0, stream>>>(
        hbuf, w0f, nullptr, nullptr, sg3, NN, 256);
    // spmm2: s2 = A*sg3 -> bf16 (N x 256)
    spmm256_plain<<<dim3(gRow), blk, 0, stream>>>(rp, edges, sg3, s2);
    // G4: g4 = relu(s2 + b0)@W1     [AK=2, A-bias b0] -> fp32 (N x 48)
    gemm_mfma<256, 4, 1, 3, 2, false, false, false><<<dim3(391), blk, 0, stream>>>(
        s2, w1f, nullptr, b0, g4, NN, 48);
    // spmm3 + b1 + log_softmax -> out
    spmm40_lsm<<<dim3(gRow), blk, 0, stream>>>(rp, edges, g4, b1, out);
    // l2 scalar
    finalize_l2<<<dim3(1), blk, 0, stream>>>(partials, gRow, out);
}

// Round 4
// 695.460 us; speedup vs baseline: 16.3661x; 1.3469x over previous
//
#include <hip/hip_runtime.h>
#include <math.h>

constexpr int NN = 100000;

using f32x4 = __attribute__((ext_vector_type(4))) float;
using s16x8 = __attribute__((ext_vector_type(8))) short;
using us8   = __attribute__((ext_vector_type(8))) unsigned short;

__device__ __forceinline__ unsigned short f2bf(float f) {
    unsigned u = __float_as_uint(f);
    unsigned r = u + 0x7FFFu + ((u >> 16) & 1u);
    return (unsigned short)(r >> 16);
}
__device__ __forceinline__ float bf2f(unsigned short u) {
    return __uint_as_float(((unsigned)u) << 16);
}

// ---------------------------------------------------------------------------
// Pack weight W[K x NC] (fp32) -> MFMA B-fragment order bf16, padded to NCpad.
// ---------------------------------------------------------------------------
__global__ __launch_bounds__(256) void wfrag_k(
    const float* __restrict__ W, short* __restrict__ Wf, int K, int NC, int NCpad)
{
    const int KK = K / 32;
    int total = (NCpad / 16) * KK * 64;
    int tid = blockIdx.x * 256 + threadIdx.x;
    if (tid >= total) return;
    int lane = tid & 63, f = tid >> 6;
    int ncg = f / KK, kk = f % KK;
    int col = ncg * 16 + (lane & 15);
    int k0  = kk * 32 + 8 * (lane >> 4);
    s16x8 o;
    #pragma unroll
    for (int j = 0; j < 8; ++j)
        o[j] = (col < NC) ? (short)f2bf(W[(size_t)(k0 + j) * NC + col]) : (short)0;
    *reinterpret_cast<s16x8*>(Wf + (size_t)tid * 8) = o;
}

// ---------------------------------------------------------------------------
// MFMA GEMM: C[M x NCout] = act(A[M x K] @ W + bias-term)
// AK: 0 = A fp32, 1 = A bf16, 2 = A bf16 with relu(a + b0[k])
// BIASMODE: 0 none, 1 +bias[col], 2 +rowsum[row]*bias[col]
// ---------------------------------------------------------------------------
template<int K, int WM, int WN, int CB, int AK, bool OBF16, int BIASMODE, bool ORELU>
__global__ __launch_bounds__(WM * WN * 64) void gemm_mfma(
    const void* __restrict__ Ain, const short* __restrict__ Wf,
    const float* __restrict__ bias, const float* __restrict__ b0,
    const float* __restrict__ rowsum, void* __restrict__ Cout, int M, int NCout)
{
    constexpr int KK = K / 32;
    const int tid = threadIdx.x;
    const int lane = tid & 63, wid = tid >> 6;
    const int wm = wid % WM, wn = wid / WM;
    const int rowBase = blockIdx.x * (WM * 64) + wm * 64;
    const int cfb = wn * CB;
    const int l15 = lane & 15, lh = lane >> 4;

    f32x4 acc[4][CB];
    #pragma unroll
    for (int i = 0; i < 4; ++i)
        #pragma unroll
        for (int j = 0; j < CB; ++j) acc[i][j] = (f32x4)0.f;

    #pragma unroll
    for (int kk = 0; kk < KK; ++kk) {
        const int k0 = kk * 32 + lh * 8;
        s16x8 a[4];
        #pragma unroll
        for (int rb = 0; rb < 4; ++rb) {
            int row = rowBase + rb * 16 + l15;
            row = row < M ? row : M - 1;
            if (AK == 0) {
                const float* ap = (const float*)Ain + (size_t)row * K + k0;
                float4 u = *reinterpret_cast<const float4*>(ap);
                float4 v = *reinterpret_cast<const float4*>(ap + 4);
                a[rb][0] = (short)f2bf(u.x); a[rb][1] = (short)f2bf(u.y);
                a[rb][2] = (short)f2bf(u.z); a[rb][3] = (short)f2bf(u.w);
                a[rb][4] = (short)f2bf(v.x); a[rb][5] = (short)f2bf(v.y);
                a[rb][6] = (short)f2bf(v.z); a[rb][7] = (short)f2bf(v.w);
            } else if (AK == 1) {
                a[rb] = *reinterpret_cast<const s16x8*>((const short*)Ain + (size_t)row * K + k0);
            } else {
                s16x8 s = *reinterpret_cast<const s16x8*>((const short*)Ain + (size_t)row * K + k0);
                float4 ba = *reinterpret_cast<const float4*>(b0 + k0);
                float4 bb = *reinterpret_cast<const float4*>(b0 + k0 + 4);
                float bv[8] = {ba.x, ba.y, ba.z, ba.w, bb.x, bb.y, bb.z, bb.w};
                #pragma unroll
                for (int j = 0; j < 8; ++j) {
                    float fv = bf2f((unsigned short)s[j]) + bv[j];
                    a[rb][j] = (short)f2bf(fmaxf(fv, 0.f));
                }
            }
        }
        s16x8 b[CB];
        #pragma unroll
        for (int cb = 0; cb < CB; ++cb)
            b[cb] = *reinterpret_cast<const s16x8*>(
                Wf + ((size_t)((cfb + cb) * KK + kk) * 64 + lane) * 8);
        #pragma unroll
        for (int rb = 0; rb < 4; ++rb)
            #pragma unroll
            for (int cb = 0; cb < CB; ++cb)
                acc[rb][cb] = __builtin_amdgcn_mfma_f32_16x16x32_bf16(
                    a[rb], b[cb], acc[rb][cb], 0, 0, 0);
    }

    #pragma unroll
    for (int cb = 0; cb < CB; ++cb) {
        int col = (cfb + cb) * 16 + l15;
        float bs = (BIASMODE != 0) ? bias[col] : 0.f;
        #pragma unroll
        for (int rb = 0; rb < 4; ++rb) {
            #pragma unroll
            for (int r = 0; r < 4; ++r) {
                int row = rowBase + rb * 16 + lh * 4 + r;
                if (row >= M) continue;
                float v = acc[rb][cb][r];
                if (BIASMODE == 1) v += bs;
                if (BIASMODE == 2) v += rowsum[row] * bs;
                if (ORELU) v = fmaxf(v, 0.f);
                if (OBF16)
                    ((unsigned short*)Cout)[(size_t)row * NCout + col] = f2bf(v);
                else
                    ((float*)Cout)[(size_t)row * NCout + col] = v;
            }
        }
    }
}

// ---------------------------------------------------------------------------
// CSR build: histogram(+rowsum) -> scan -> counting-sort scatter.
// ---------------------------------------------------------------------------
__global__ __launch_bounds__(256) void hist_k(
    const int* __restrict__ row, const float* __restrict__ val,
    int* __restrict__ cnt, float* __restrict__ rowsum, int E)
{
    int e = blockIdx.x * 256 + threadIdx.x;
    if (e < E) {
        int r = row[e];
        atomicAdd(&cnt[r], 1);
        unsafeAtomicAdd(&rowsum[r], val[e]);
    }
}

__global__ __launch_bounds__(256) void scan_blk(
    const int* __restrict__ cnt, int* __restrict__ rp, int* __restrict__ bsums, int n)
{
    const int t = threadIdx.x;
    const int lane = t & 63, wid = t >> 6;
    const int base = blockIdx.x * 1024 + t * 4;
    int a0 = 0, a1 = 0, a2 = 0, a3 = 0;
    if (base + 3 < n) {
        int4 v = *reinterpret_cast<const int4*>(&cnt[base]);
        a0 = v.x; a1 = v.y; a2 = v.z; a3 = v.w;
    } else {
        if (base + 0 < n) a0 = cnt[base + 0];
        if (base + 1 < n) a1 = cnt[base + 1];
        if (base + 2 < n) a2 = cnt[base + 2];
        if (base + 3 < n) a3 = cnt[base + 3];
    }
    int s0 = a0, s1 = s0 + a1, s2 = s1 + a2, s3 = s2 + a3;
    int v = s3;
    #pragma unroll
    for (int o = 1; o < 64; o <<= 1) {
        int u = __shfl_up(v, o);
        if (lane >= o) v += u;
    }
    __shared__ int wtot[4];
    if (lane == 63) wtot[wid] = v;
    __syncthreads();
    int woff = 0;
    #pragma unroll
    for (int w = 0; w < 4; ++w) if (w < wid) woff += wtot[w];
    int texcl = woff + v - s3;
    if (base + 0 < n) rp[base + 0] = texcl;
    if (base + 1 < n) rp[base + 1] = texcl + s0;
    if (base + 2 < n) rp[base + 2] = texcl + s1;
    if (base + 3 < n) rp[base + 3] = texcl + s2;
    if (t == 255) bsums[blockIdx.x] = woff + v;
}

__global__ void scan_mid(const int* __restrict__ bsums, int* __restrict__ boff, int nb)
{
    if (threadIdx.x == 0 && blockIdx.x == 0) {
        int run = 0;
        for (int b = 0; b < nb; ++b) { boff[b] = run; run += bsums[b]; }
    }
}

__global__ __launch_bounds__(256) void scan_add(
    int* __restrict__ rp, const int* __restrict__ boff, int n, int E)
{
    int i = blockIdx.x * 256 + threadIdx.x;
    if (i < n) rp[i] += boff[i >> 10];
    if (i == 0) rp[n] = E;
}

__global__ __launch_bounds__(256) void scatter_k(
    const int* __restrict__ row, const int* __restrict__ col,
    const float* __restrict__ val, const int* __restrict__ rp,
    int* __restrict__ cnt, int2* __restrict__ edges, int E)
{
    int e = blockIdx.x * 256 + threadIdx.x;
    if (e >= E) return;
    int r = row[e];
    int p = rp[r] + atomicAdd(&cnt[r], 1);
    edges[p] = make_int2(col[e], __float_as_int(val[e]));
}

// ---------------------------------------------------------------------------
// CSR SpMM gather, F=128 bf16: 16 lanes per row (4 rows/wave), ushort8/lane.
// ---------------------------------------------------------------------------
__global__ __launch_bounds__(256) void spmm128(
    const int* __restrict__ rp, const int2* __restrict__ edges,
    const unsigned short* __restrict__ mat, unsigned short* __restrict__ out)
{
    int gid = blockIdx.x * 256 + threadIdx.x;
    int r = gid >> 4, sl = gid & 15;
    if (r >= NN) return;
    const int beg = rp[r], end = rp[r + 1];
    float acc[8] = {};
    for (int e = beg; e < end; ++e) {
        int2 cv = edges[e];
        float v = __int_as_float(cv.y);
        us8 f = *reinterpret_cast<const us8*>(mat + (size_t)cv.x * 128 + sl * 8);
        #pragma unroll
        for (int j = 0; j < 8; ++j) acc[j] += v * bf2f(f[j]);
    }
    us8 o;
    #pragma unroll
    for (int j = 0; j < 8; ++j) o[j] = f2bf(acc[j]);
    *reinterpret_cast<us8*>(out + (size_t)r * 128 + sl * 8) = o;
}

// ---------------------------------------------------------------------------
// Sampling from z[N x 256] bf16: h = mean + (softplus(s)+0.01)*eps, l2 partials.
// Thread = (row, 8-feature chunk).
// ---------------------------------------------------------------------------
__global__ __launch_bounds__(256) void sample_k(
    const unsigned short* __restrict__ z, const float* __restrict__ eps,
    unsigned short* __restrict__ h, float* __restrict__ partials)
{
    int idx = blockIdx.x * 256 + threadIdx.x;
    int r = idx >> 4, j = idx & 15;
    const unsigned short* zr = z + (size_t)r * 256 + j * 8;
    us8 mz = *reinterpret_cast<const us8*>(zr);
    us8 sz = *reinterpret_cast<const us8*>(zr + 128);
    const float* ep = eps + (size_t)r * 128 + j * 8;
    float4 e0 = *reinterpret_cast<const float4*>(ep);
    float4 e1 = *reinterpret_cast<const float4*>(ep + 4);
    float ev[8] = {e0.x, e0.y, e0.z, e0.w, e1.x, e1.y, e1.z, e1.w};
    float p = 0.f;
    us8 hv;
    #pragma unroll
    for (int k = 0; k < 8; ++k) {
        float mean = bf2f(mz[k]);
        float s    = bf2f(sz[k]);
        float sp   = fmaxf(s, 0.f) + log1pf(expf(-fabsf(s)));
        float sd   = sp + 0.01f;
        float hh   = mean + sd * ev[k];
        hv[k] = f2bf(hh);
        p += 0.5f * hh * hh - 0.5f * ev[k] * ev[k] - logf(sd);
    }
    *reinterpret_cast<us8*>(h + (size_t)r * 128 + j * 8) = hv;
    #pragma unroll
    for (int o = 32; o > 0; o >>= 1) p += __shfl_xor(p, o);
    __shared__ float ws[4];
    if ((threadIdx.x & 63) == 0) ws[threadIdx.x >> 6] = p;
    __syncthreads();
    if (threadIdx.x == 0)
        partials[blockIdx.x] = ws[0] + ws[1] + ws[2] + ws[3];
}

// ---------------------------------------------------------------------------
// CSR SpMM F=40 (fp32, stride 48) + b1 + log_softmax: 16 lanes/row, float4.
// ---------------------------------------------------------------------------
__global__ __launch_bounds__(256) void spmm40_lsm(
    const int* __restrict__ rp, const int2* __restrict__ edges,
    const float* __restrict__ mat, const float* __restrict__ b1,
    float* __restrict__ out)
{
    int gid = blockIdx.x * 256 + threadIdx.x;
    int r = gid >> 4, sl = gid & 15;
    const int beg = rp[r], end = rp[r + 1];
    float4 acc = make_float4(0.f, 0.f, 0.f, 0.f);
    for (int e = beg; e < end; ++e) {
        int2 cv = edges[e];
        float v = __int_as_float(cv.y);
        if (sl < 10) {
            float4 m4 = *reinterpret_cast<const float4*>(mat + (size_t)cv.x * 48 + sl * 4);
            acc.x += v * m4.x; acc.y += v * m4.y; acc.z += v * m4.z; acc.w += v * m4.w;
        }
    }
    float xv[4] = {-1e30f, -1e30f, -1e30f, -1e30f};
    if (sl < 10) {
        float4 bb = *reinterpret_cast<const float4*>(b1 + sl * 4);
        xv[0] = acc.x + bb.x; xv[1] = acc.y + bb.y;
        xv[2] = acc.z + bb.z; xv[3] = acc.w + bb.w;
    }
    float m = fmaxf(fmaxf(xv[0], xv[1]), fmaxf(xv[2], xv[3]));
    #pragma unroll
    for (int o = 1; o < 16; o <<= 1) m = fmaxf(m, __shfl_xor(m, o, 16));
    float ssum = 0.f;
    #pragma unroll
    for (int k = 0; k < 4; ++k) ssum += (sl < 10) ? expf(xv[k] - m) : 0.f;
    #pragma unroll
    for (int o = 1; o < 16; o <<= 1) ssum += __shfl_xor(ssum, o, 16);
    if (sl < 10) {
        float lse = m + logf(ssum);
        float4 o4 = make_float4(xv[0] - lse, xv[1] - lse, xv[2] - lse, xv[3] - lse);
        *reinterpret_cast<float4*>(out + (size_t)r * 40 + sl * 4) = o4;
    }
}

__global__ __launch_bounds__(256) void finalize_l2(
    const float* __restrict__ partials, int np, float* __restrict__ out)
{
    double a = 0.0;
    for (int i = threadIdx.x; i < np; i += 256) a += (double)partials[i];
    #pragma unroll
    for (int o = 32; o > 0; o >>= 1) a += __shfl_xor(a, o);
    __shared__ double ws[4];
    if ((threadIdx.x & 63) == 0) ws[threadIdx.x >> 6] = a;
    __syncthreads();
    if (threadIdx.x == 0)
        out[(size_t)NN * 40] = (float)((ws[0] + ws[1] + ws[2] + ws[3]) / (double)NN);
}

// ---------------------------------------------------------------------------
extern "C" void kernel_launch(void* const* d_in, const int* in_sizes, int n_in,
                              void* d_out, int out_size, void* d_ws, size_t ws_size,
                              hipStream_t stream)
{
    const float* x    = (const float*)d_in[0];
    const int*   arow = (const int*)d_in[1];
    const int*   acol = (const int*)d_in[2];
    const float* aval = (const float*)d_in[3];
    const float* eps  = (const float*)d_in[4];
    const float* Wz1  = (const float*)d_in[5];
    const float* bz1  = (const float*)d_in[6];
    const float* Wz2  = (const float*)d_in[7];
    const float* bz2  = (const float*)d_in[8];
    const float* W0   = (const float*)d_in[9];
    const float* b0   = (const float*)d_in[10];
    const float* W1   = (const float*)d_in[11];
    const float* b1   = (const float*)d_in[12];
    float* out = (float*)d_out;
    const int E = in_sizes[1];

    // ---- workspace (reused buffers) ----
    char* p = (char*)d_ws;
    auto alloc = [&](size_t bytes) {
        char* q = p;
        p += (bytes + 15) & ~(size_t)15;
        return (void*)q;
    };
    int2* edges    = (int2*)alloc((size_t)E * 8);
    int*  rp       = (int*)alloc((size_t)(NN + 4) * 4);
    int*  cnt      = (int*)alloc((size_t)NN * 4);
    float* rowsum  = (float*)alloc((size_t)NN * 4);
    int*  bsums    = (int*)alloc(128 * 4);
    int*  boff     = (int*)alloc(128 * 4);
    float* partials = (float*)alloc(6250 * 4);
    unsigned short* bufT = (unsigned short*)alloc((size_t)NN * 128 * 2); // t1 / ah
    unsigned short* bufU = (unsigned short*)alloc((size_t)NN * 128 * 2); // at1 / h
    unsigned short* bufZ = (unsigned short*)alloc((size_t)NN * 256 * 2); // z / s2
    float* g4      = (float*)alloc((size_t)NN * 48 * 4);
    short* wz1f    = (short*)alloc(8  * 4 * 64 * 8 * 2);
    short* wz2f    = (short*)alloc(16 * 4 * 64 * 8 * 2);
    short* w0f     = (short*)alloc(16 * 4 * 64 * 8 * 2);
    short* w1f     = (short*)alloc(3  * 8 * 64 * 8 * 2);

    dim3 blk(256);
    const int gE = (E + 255) / 256;
    const int nScan = (NN + 1023) / 1024;
    const int gSp = (NN * 16) / 256;   // 6250: 16 lanes per row

    // --- weight fragment packing ---
    wfrag_k<<<dim3((8  * 4 * 64 + 255) / 256), blk, 0, stream>>>(Wz1, wz1f, 128, 128, 128);
    wfrag_k<<<dim3((16 * 4 * 64 + 255) / 256), blk, 0, stream>>>(Wz2, wz2f, 128, 256, 256);
    wfrag_k<<<dim3((16 * 4 * 64 + 255) / 256), blk, 0, stream>>>(W0,  w0f,  128, 256, 256);
    wfrag_k<<<dim3((3  * 8 * 64 + 255) / 256), blk, 0, stream>>>(W1,  w1f,  256, 40, 48);

    // --- CSR build (+ rowsum) ---
    hipMemsetAsync(cnt, 0, (size_t)NN * sizeof(int), stream);
    hipMemsetAsync(rowsum, 0, (size_t)NN * sizeof(float), stream);
    hist_k<<<dim3(gE), blk, 0, stream>>>(arow, aval, cnt, rowsum, E);
    scan_blk<<<dim3(nScan), blk, 0, stream>>>(cnt, rp, bsums, NN);
    scan_mid<<<dim3(1), dim3(64), 0, stream>>>(bsums, boff, nScan);
    scan_add<<<dim3((NN + 256) / 256), blk, 0, stream>>>(rp, boff, NN, E);
    hipMemsetAsync(cnt, 0, (size_t)NN * sizeof(int), stream);
    scatter_k<<<dim3(gE), blk, 0, stream>>>(arow, acol, aval, rp, cnt, edges, E);

    // --- pipeline (SpMM pushed left through linear maps) ---
    // G1: t1 = relu(x@Wz1 + bz1) -> bufT (N x 128 bf16)
    gemm_mfma<128, 2, 2, 4, 0, true, 1, true><<<dim3(782), blk, 0, stream>>>(
        x, wz1f, bz1, nullptr, nullptr, bufT, NN, 128);
    // at1 = S @ t1 -> bufU
    spmm128<<<dim3(gSp), blk, 0, stream>>>(rp, edges, bufT, bufU);
    // z = at1@Wz2 + rowsum*bz2 -> bufZ (N x 256 bf16)
    gemm_mfma<128, 1, 4, 4, 1, true, 2, false><<<dim3(1563), blk, 0, stream>>>(
        bufU, wz2f, bz2, nullptr, rowsum, bufZ, NN, 256);
    // sample: h -> bufU (overwrites at1), l2 partials
    sample_k<<<dim3(gSp), blk, 0, stream>>>(bufZ, eps, bufU, partials);
    // ah = S @ h -> bufT (overwrites t1)
    spmm128<<<dim3(gSp), blk, 0, stream>>>(rp, edges, bufU, bufT);
    // s2 = ah@W0 -> bufZ (overwrites z)
    gemm_mfma<128, 1, 4, 4, 1, true, 0, false><<<dim3(1563), blk, 0, stream>>>(
        bufT, w0f, nullptr, nullptr, nullptr, bufZ, NN, 256);
    // g4 = relu(s2 + b0)@W1 -> fp32 (N x 48)
    gemm_mfma<256, 4, 1, 3, 2, false, 0, false><<<dim3(391), blk, 0, stream>>>(
        bufZ, w1f, nullptr, b0, nullptr, g4, NN, 48);
    // spmm3 + b1 + log_softmax -> out
    spmm40_lsm<<<dim3(gSp), blk, 0, stream>>>(rp, edges, g4, b1, out);
    // l2 scalar
    finalize_l2<<<dim3(1), blk, 0, stream>>>(partials, 6250, out);
}

// Round 5
// 625.605 us; speedup vs baseline: 18.1935x; 1.1117x over previous
//
#include <hip/hip_runtime.h>
#include <math.h>

constexpr int NN = 100000;
constexpr int NCHUNK = 64;
constexpr int RROWS  = 12500;   // rows per range (8 ranges)

using f32x4 = __attribute__((ext_vector_type(4))) float;
using s16x8 = __attribute__((ext_vector_type(8))) short;
using us8   = __attribute__((ext_vector_type(8))) unsigned short;

__device__ __forceinline__ unsigned short f2bf(float f) {
    unsigned u = __float_as_uint(f);
    unsigned r = u + 0x7FFFu + ((u >> 16) & 1u);
    return (unsigned short)(r >> 16);
}
__device__ __forceinline__ float bf2f(unsigned short u) {
    return __uint_as_float(((unsigned)u) << 16);
}

// ---------------------------------------------------------------------------
// Pack weight W[K x NC] (fp32) -> MFMA B-fragment order bf16, padded to NCpad.
// ---------------------------------------------------------------------------
__global__ __launch_bounds__(256) void wfrag_k(
    const float* __restrict__ W, short* __restrict__ Wf, int K, int NC, int NCpad)
{
    const int KK = K / 32;
    int total = (NCpad / 16) * KK * 64;
    int tid = blockIdx.x * 256 + threadIdx.x;
    if (tid >= total) return;
    int lane = tid & 63, f = tid >> 6;
    int ncg = f / KK, kk = f % KK;
    int col = ncg * 16 + (lane & 15);
    int k0  = kk * 32 + 8 * (lane >> 4);
    s16x8 o;
    #pragma unroll
    for (int j = 0; j < 8; ++j)
        o[j] = (col < NC) ? (short)f2bf(W[(size_t)(k0 + j) * NC + col]) : (short)0;
    *reinterpret_cast<s16x8*>(Wf + (size_t)tid * 8) = o;
}

// ---------------------------------------------------------------------------
// MFMA GEMM: C[M x NCout] = act(A[M x K] @ W + bias-term)
// AK: 0 = A fp32, 1 = A bf16, 2 = A bf16 with relu(a + b0[k])
// BIASMODE: 0 none, 1 +bias[col], 2 +rowsum[row]*bias[col]
// ---------------------------------------------------------------------------
template<int K, int WM, int WN, int CB, int AK, bool OBF16, int BIASMODE, bool ORELU>
__global__ __launch_bounds__(WM * WN * 64) void gemm_mfma(
    const void* __restrict__ Ain, const short* __restrict__ Wf,
    const float* __restrict__ bias, const float* __restrict__ b0,
    const float* __restrict__ rowsum, void* __restrict__ Cout, int M, int NCout)
{
    constexpr int KK = K / 32;
    const int tid = threadIdx.x;
    const int lane = tid & 63, wid = tid >> 6;
    const int wm = wid % WM, wn = wid / WM;
    const int rowBase = blockIdx.x * (WM * 64) + wm * 64;
    const int cfb = wn * CB;
    const int l15 = lane & 15, lh = lane >> 4;

    f32x4 acc[4][CB];
    #pragma unroll
    for (int i = 0; i < 4; ++i)
        #pragma unroll
        for (int j = 0; j < CB; ++j) acc[i][j] = (f32x4)0.f;

    #pragma unroll
    for (int kk = 0; kk < KK; ++kk) {
        const int k0 = kk * 32 + lh * 8;
        s16x8 a[4];
        #pragma unroll
        for (int rb = 0; rb < 4; ++rb) {
            int row = rowBase + rb * 16 + l15;
            row = row < M ? row : M - 1;
            if (AK == 0) {
                const float* ap = (const float*)Ain + (size_t)row * K + k0;
                float4 u = *reinterpret_cast<const float4*>(ap);
                float4 v = *reinterpret_cast<const float4*>(ap + 4);
                a[rb][0] = (short)f2bf(u.x); a[rb][1] = (short)f2bf(u.y);
                a[rb][2] = (short)f2bf(u.z); a[rb][3] = (short)f2bf(u.w);
                a[rb][4] = (short)f2bf(v.x); a[rb][5] = (short)f2bf(v.y);
                a[rb][6] = (short)f2bf(v.z); a[rb][7] = (short)f2bf(v.w);
            } else if (AK == 1) {
                a[rb] = *reinterpret_cast<const s16x8*>((const short*)Ain + (size_t)row * K + k0);
            } else {
                s16x8 s = *reinterpret_cast<const s16x8*>((const short*)Ain + (size_t)row * K + k0);
                float4 ba = *reinterpret_cast<const float4*>(b0 + k0);
                float4 bb = *reinterpret_cast<const float4*>(b0 + k0 + 4);
                float bv[8] = {ba.x, ba.y, ba.z, ba.w, bb.x, bb.y, bb.z, bb.w};
                #pragma unroll
                for (int j = 0; j < 8; ++j) {
                    float fv = bf2f((unsigned short)s[j]) + bv[j];
                    a[rb][j] = (short)f2bf(fmaxf(fv, 0.f));
                }
            }
        }
        s16x8 b[CB];
        #pragma unroll
        for (int cb = 0; cb < CB; ++cb)
            b[cb] = *reinterpret_cast<const s16x8*>(
                Wf + ((size_t)((cfb + cb) * KK + kk) * 64 + lane) * 8);
        #pragma unroll
        for (int rb = 0; rb < 4; ++rb)
            #pragma unroll
            for (int cb = 0; cb < CB; ++cb)
                acc[rb][cb] = __builtin_amdgcn_mfma_f32_16x16x32_bf16(
                    a[rb], b[cb], acc[rb][cb], 0, 0, 0);
    }

    #pragma unroll
    for (int cb = 0; cb < CB; ++cb) {
        int col = (cfb + cb) * 16 + l15;
        float bs = (BIASMODE != 0) ? bias[col] : 0.f;
        #pragma unroll
        for (int rb = 0; rb < 4; ++rb) {
            #pragma unroll
            for (int r = 0; r < 4; ++r) {
                int row = rowBase + rb * 16 + lh * 4 + r;
                if (row >= M) continue;
                float v = acc[rb][cb][r];
                if (BIASMODE == 1) v += bs;
                if (BIASMODE == 2) v += rowsum[row] * bs;
                if (ORELU) v = fmaxf(v, 0.f);
                if (OBF16)
                    ((unsigned short*)Cout)[(size_t)row * NCout + col] = f2bf(v);
                else
                    ((float*)Cout)[(size_t)row * NCout + col] = v;
            }
        }
    }
}

// ---------------------------------------------------------------------------
// Atomic-free CSR build.
// hist_part: (chunk, range) blocks; LDS histogram of 12500-row range.
// ---------------------------------------------------------------------------
__global__ __launch_bounds__(256) void hist_part(
    const int* __restrict__ row, int* __restrict__ part, int E, int chunkE)
{
    __shared__ int lcnt[RROWS];
    const int chunk = blockIdx.x;
    const int rowLo = blockIdx.y * RROWS;
    for (int i = threadIdx.x; i < RROWS; i += 256) lcnt[i] = 0;
    __syncthreads();
    const int e0 = chunk * chunkE;
    const int e1 = min(e0 + chunkE, E);
    for (int e = e0 + threadIdx.x; e < e1; e += 256) {
        int r = row[e] - rowLo;
        if ((unsigned)r < (unsigned)RROWS) atomicAdd(&lcnt[r], 1);
    }
    __syncthreads();
    int* dst = part + (size_t)chunk * NN + rowLo;
    for (int i = threadIdx.x; i < RROWS; i += 256) dst[i] = lcnt[i];
}

// Per-row running prefix across chunks (in place) + total -> cnt.
__global__ __launch_bounds__(256) void chunk_scan(
    int* __restrict__ part, int* __restrict__ cnt)
{
    int r = blockIdx.x * 256 + threadIdx.x;
    if (r >= NN) return;
    int run = 0;
    #pragma unroll 8
    for (int c = 0; c < NCHUNK; ++c) {
        int* p = part + (size_t)c * NN + r;
        int v = *p;
        *p = run;
        run += v;
    }
    cnt[r] = run;
}

__global__ __launch_bounds__(256) void scan_blk(
    const int* __restrict__ cnt, int* __restrict__ rp, int* __restrict__ bsums, int n)
{
    const int t = threadIdx.x;
    const int lane = t & 63, wid = t >> 6;
    const int base = blockIdx.x * 1024 + t * 4;
    int a0 = 0, a1 = 0, a2 = 0, a3 = 0;
    if (base + 3 < n) {
        int4 v = *reinterpret_cast<const int4*>(&cnt[base]);
        a0 = v.x; a1 = v.y; a2 = v.z; a3 = v.w;
    } else {
        if (base + 0 < n) a0 = cnt[base + 0];
        if (base + 1 < n) a1 = cnt[base + 1];
        if (base + 2 < n) a2 = cnt[base + 2];
        if (base + 3 < n) a3 = cnt[base + 3];
    }
    int s0 = a0, s1 = s0 + a1, s2 = s1 + a2, s3 = s2 + a3;
    int v = s3;
    #pragma unroll
    for (int o = 1; o < 64; o <<= 1) {
        int u = __shfl_up(v, o);
        if (lane >= o) v += u;
    }
    __shared__ int wtot[4];
    if (lane == 63) wtot[wid] = v;
    __syncthreads();
    int woff = 0;
    #pragma unroll
    for (int w = 0; w < 4; ++w) if (w < wid) woff += wtot[w];
    int texcl = woff + v - s3;
    if (base + 0 < n) rp[base + 0] = texcl;
    if (base + 1 < n) rp[base + 1] = texcl + s0;
    if (base + 2 < n) rp[base + 2] = texcl + s1;
    if (base + 3 < n) rp[base + 3] = texcl + s2;
    if (t == 255) bsums[blockIdx.x] = woff + v;
}

__global__ void scan_mid(const int* __restrict__ bsums, int* __restrict__ boff, int nb)
{
    if (threadIdx.x == 0 && blockIdx.x == 0) {
        int run = 0;
        for (int b = 0; b < nb; ++b) { boff[b] = run; run += bsums[b]; }
    }
}

__global__ __launch_bounds__(256) void scan_add(
    int* __restrict__ rp, const int* __restrict__ boff, int n, int E)
{
    int i = blockIdx.x * 256 + threadIdx.x;
    if (i < n) rp[i] += boff[i >> 10];
    if (i == 0) rp[n] = E;
}

// scatter with LDS-local position counters (no global atomics).
__global__ __launch_bounds__(256) void scatter_part(
    const int* __restrict__ row, const int* __restrict__ col,
    const float* __restrict__ val, const int* __restrict__ rp,
    const int* __restrict__ part, int2* __restrict__ edges, int E, int chunkE)
{
    __shared__ int lcnt[RROWS];
    const int chunk = blockIdx.x;
    const int rowLo = blockIdx.y * RROWS;
    for (int i = threadIdx.x; i < RROWS; i += 256) lcnt[i] = 0;
    __syncthreads();
    const int e0 = chunk * chunkE;
    const int e1 = min(e0 + chunkE, E);
    const int* choff = part + (size_t)chunk * NN;
    for (int e = e0 + threadIdx.x; e < e1; e += 256) {
        int r = row[e];
        int lr = r - rowLo;
        if ((unsigned)lr < (unsigned)RROWS) {
            int local = atomicAdd(&lcnt[lr], 1);
            int p = rp[r] + choff[r] + local;
            edges[p] = make_int2(col[e], __float_as_int(val[e]));
        }
    }
}

// ---------------------------------------------------------------------------
// CSR SpMM gather, F=128 bf16: 16 lanes per row (4 rows/wave), ushort8/lane.
// RS: also emit rowsum[r] = sum of edge vals (lane 0 of each row group).
// ---------------------------------------------------------------------------
template<bool RS>
__global__ __launch_bounds__(256) void spmm128(
    const int* __restrict__ rp, const int2* __restrict__ edges,
    const unsigned short* __restrict__ mat, unsigned short* __restrict__ out,
    float* __restrict__ rowsum)
{
    int gid = blockIdx.x * 256 + threadIdx.x;
    int r = gid >> 4, sl = gid & 15;
    if (r >= NN) return;
    const int beg = rp[r], end = rp[r + 1];
    float acc[8] = {};
    float vs = 0.f;
    for (int e = beg; e < end; ++e) {
        int2 cv = edges[e];
        float v = __int_as_float(cv.y);
        if (RS) vs += v;
        us8 f = *reinterpret_cast<const us8*>(mat + (size_t)cv.x * 128 + sl * 8);
        #pragma unroll
        for (int j = 0; j < 8; ++j) acc[j] += v * bf2f(f[j]);
    }
    us8 o;
    #pragma unroll
    for (int j = 0; j < 8; ++j) o[j] = f2bf(acc[j]);
    *reinterpret_cast<us8*>(out + (size_t)r * 128 + sl * 8) = o;
    if (RS && sl == 0) rowsum[r] = vs;
}

// ---------------------------------------------------------------------------
// Sampling from z[N x 256] bf16: h = mean + (softplus(s)+0.01)*eps, l2 partials.
// ---------------------------------------------------------------------------
__global__ __launch_bounds__(256) void sample_k(
    const unsigned short* __restrict__ z, const float* __restrict__ eps,
    unsigned short* __restrict__ h, float* __restrict__ partials)
{
    int idx = blockIdx.x * 256 + threadIdx.x;
    int r = idx >> 4, j = idx & 15;
    const unsigned short* zr = z + (size_t)r * 256 + j * 8;
    us8 mz = *reinterpret_cast<const us8*>(zr);
    us8 sz = *reinterpret_cast<const us8*>(zr + 128);
    const float* ep = eps + (size_t)r * 128 + j * 8;
    float4 e0 = *reinterpret_cast<const float4*>(ep);
    float4 e1 = *reinterpret_cast<const float4*>(ep + 4);
    float ev[8] = {e0.x, e0.y, e0.z, e0.w, e1.x, e1.y, e1.z, e1.w};
    float p = 0.f;
    us8 hv;
    #pragma unroll
    for (int k = 0; k < 8; ++k) {
        float mean = bf2f(mz[k]);
        float s    = bf2f(sz[k]);
        float sp   = fmaxf(s, 0.f) + log1pf(expf(-fabsf(s)));
        float sd   = sp + 0.01f;
        float hh   = mean + sd * ev[k];
        hv[k] = f2bf(hh);
        p += 0.5f * hh * hh - 0.5f * ev[k] * ev[k] - logf(sd);
    }
    *reinterpret_cast<us8*>(h + (size_t)r * 128 + j * 8) = hv;
    #pragma unroll
    for (int o = 32; o > 0; o >>= 1) p += __shfl_xor(p, o);
    __shared__ float ws[4];
    if ((threadIdx.x & 63) == 0) ws[threadIdx.x >> 6] = p;
    __syncthreads();
    if (threadIdx.x == 0)
        partials[blockIdx.x] = ws[0] + ws[1] + ws[2] + ws[3];
}

// ---------------------------------------------------------------------------
// CSR SpMM F=40 (fp32, stride 48) + b1 + log_softmax: 16 lanes/row, float4.
// ---------------------------------------------------------------------------
__global__ __launch_bounds__(256) void spmm40_lsm(
    const int* __restrict__ rp, const int2* __restrict__ edges,
    const float* __restrict__ mat, const float* __restrict__ b1,
    float* __restrict__ out)
{
    int gid = blockIdx.x * 256 + threadIdx.x;
    int r = gid >> 4, sl = gid & 15;
    const int beg = rp[r], end = rp[r + 1];
    float4 acc = make_float4(0.f, 0.f, 0.f, 0.f);
    for (int e = beg; e < end; ++e) {
        int2 cv = edges[e];
        float v = __int_as_float(cv.y);
        if (sl < 10) {
            float4 m4 = *reinterpret_cast<const float4*>(mat + (size_t)cv.x * 48 + sl * 4);
            acc.x += v * m4.x; acc.y += v * m4.y; acc.z += v * m4.z; acc.w += v * m4.w;
        }
    }
    float xv[4] = {-1e30f, -1e30f, -1e30f, -1e30f};
    if (sl < 10) {
        float4 bb = *reinterpret_cast<const float4*>(b1 + sl * 4);
        xv[0] = acc.x + bb.x; xv[1] = acc.y + bb.y;
        xv[2] = acc.z + bb.z; xv[3] = acc.w + bb.w;
    }
    float m = fmaxf(fmaxf(xv[0], xv[1]), fmaxf(xv[2], xv[3]));
    #pragma unroll
    for (int o = 1; o < 16; o <<= 1) m = fmaxf(m, __shfl_xor(m, o, 16));
    float ssum = 0.f;
    #pragma unroll
    for (int k = 0; k < 4; ++k) ssum += (sl < 10) ? expf(xv[k] - m) : 0.f;
    #pragma unroll
    for (int o = 1; o < 16; o <<= 1) ssum += __shfl_xor(ssum, o, 16);
    if (sl < 10) {
        float lse = m + logf(ssum);
        float4 o4 = make_float4(xv[0] - lse, xv[1] - lse, xv[2] - lse, xv[3] - lse);
        *reinterpret_cast<float4*>(out + (size_t)r * 40 + sl * 4) = o4;
    }
}

__global__ __launch_bounds__(256) void finalize_l2(
    const float* __restrict__ partials, int np, float* __restrict__ out)
{
    double a = 0.0;
    for (int i = threadIdx.x; i < np; i += 256) a += (double)partials[i];
    #pragma unroll
    for (int o = 32; o > 0; o >>= 1) a += __shfl_xor(a, o);
    __shared__ double ws[4];
    if ((threadIdx.x & 63) == 0) ws[threadIdx.x >> 6] = a;
    __syncthreads();
    if (threadIdx.x == 0)
        out[(size_t)NN * 40] = (float)((ws[0] + ws[1] + ws[2] + ws[3]) / (double)NN);
}

// ---------------------------------------------------------------------------
extern "C" void kernel_launch(void* const* d_in, const int* in_sizes, int n_in,
                              void* d_out, int out_size, void* d_ws, size_t ws_size,
                              hipStream_t stream)
{
    const float* x    = (const float*)d_in[0];
    const int*   arow = (const int*)d_in[1];
    const int*   acol = (const int*)d_in[2];
    const float* aval = (const float*)d_in[3];
    const float* eps  = (const float*)d_in[4];
    const float* Wz1  = (const float*)d_in[5];
    const float* bz1  = (const float*)d_in[6];
    const float* Wz2  = (const float*)d_in[7];
    const float* bz2  = (const float*)d_in[8];
    const float* W0   = (const float*)d_in[9];
    const float* b0   = (const float*)d_in[10];
    const float* W1   = (const float*)d_in[11];
    const float* b1   = (const float*)d_in[12];
    float* out = (float*)d_out;
    const int E = in_sizes[1];

    // ---- workspace ----
    char* p = (char*)d_ws;
    auto alloc = [&](size_t bytes) {
        char* q = p;
        p += (bytes + 15) & ~(size_t)15;
        return (void*)q;
    };
    int2* edges    = (int2*)alloc((size_t)E * 8);
    int*  part     = (int*)alloc((size_t)NCHUNK * NN * 4);   // 25.6 MB
    int*  rp       = (int*)alloc((size_t)(NN + 4) * 4);
    int*  cnt      = (int*)alloc((size_t)NN * 4);
    float* rowsum  = (float*)alloc((size_t)NN * 4);
    int*  bsums    = (int*)alloc(128 * 4);
    int*  boff     = (int*)alloc(128 * 4);
    float* partials = (float*)alloc(6250 * 4);
    unsigned short* bufT = (unsigned short*)alloc((size_t)NN * 128 * 2); // t1 / ah
    unsigned short* bufU = (unsigned short*)alloc((size_t)NN * 128 * 2); // at1 / h
    unsigned short* bufZ = (unsigned short*)alloc((size_t)NN * 256 * 2); // z / s2
    float* g4      = (float*)alloc((size_t)NN * 48 * 4);
    short* wz1f    = (short*)alloc(8  * 4 * 64 * 8 * 2);
    short* wz2f    = (short*)alloc(16 * 4 * 64 * 8 * 2);
    short* w0f     = (short*)alloc(16 * 4 * 64 * 8 * 2);
    short* w1f     = (short*)alloc(3  * 8 * 64 * 8 * 2);

    dim3 blk(256);
    const int nScan = (NN + 1023) / 1024;
    const int gSp = (NN * 16) / 256;                 // 6250
    const int chunkE = (E + NCHUNK - 1) / NCHUNK;    // 25000
    const dim3 gPart(NCHUNK, NN / RROWS);            // 64 x 8

    // --- weight fragment packing ---
    wfrag_k<<<dim3((8  * 4 * 64 + 255) / 256), blk, 0, stream>>>(Wz1, wz1f, 128, 128, 128);
    wfrag_k<<<dim3((16 * 4 * 64 + 255) / 256), blk, 0, stream>>>(Wz2, wz2f, 128, 256, 256);
    wfrag_k<<<dim3((16 * 4 * 64 + 255) / 256), blk, 0, stream>>>(W0,  w0f,  128, 256, 256);
    wfrag_k<<<dim3((3  * 8 * 64 + 255) / 256), blk, 0, stream>>>(W1,  w1f,  256, 40, 48);

    // --- CSR build (atomic-free) ---
    hist_part<<<gPart, blk, 0, stream>>>(arow, part, E, chunkE);
    chunk_scan<<<dim3((NN + 255) / 256), blk, 0, stream>>>(part, cnt);
    scan_blk<<<dim3(nScan), blk, 0, stream>>>(cnt, rp, bsums, NN);
    scan_mid<<<dim3(1), dim3(64), 0, stream>>>(bsums, boff, nScan);
    scan_add<<<dim3((NN + 256) / 256), blk, 0, stream>>>(rp, boff, NN, E);
    scatter_part<<<gPart, blk, 0, stream>>>(arow, acol, aval, rp, part, edges, E, chunkE);

    // --- pipeline ---
    // G1: t1 = relu(x@Wz1 + bz1) -> bufT (N x 128 bf16)
    gemm_mfma<128, 2, 2, 4, 0, true, 1, true><<<dim3(782), blk, 0, stream>>>(
        x, wz1f, bz1, nullptr, nullptr, bufT, NN, 128);
    // at1 = S @ t1 -> bufU  (also emits rowsum)
    spmm128<true><<<dim3(gSp), blk, 0, stream>>>(rp, edges, bufT, bufU, rowsum);
    // z = at1@Wz2 + rowsum*bz2 -> bufZ (N x 256 bf16)
    gemm_mfma<128, 1, 4, 4, 1, true, 2, false><<<dim3(1563), blk, 0, stream>>>(
        bufU, wz2f, bz2, nullptr, rowsum, bufZ, NN, 256);
    // sample: h -> bufU, l2 partials
    sample_k<<<dim3(gSp), blk, 0, stream>>>(bufZ, eps, bufU, partials);
    // ah = S @ h -> bufT
    spmm128<false><<<dim3(gSp), blk, 0, stream>>>(rp, edges, bufU, bufT, nullptr);
    // s2 = ah@W0 -> bufZ
    gemm_mfma<128, 1, 4, 4, 1, true, 0, false><<<dim3(1563), blk, 0, stream>>>(
        bufT, w0f, nullptr, nullptr, nullptr, bufZ, NN, 256);
    // g4 = relu(s2 + b0)@W1 -> fp32 (N x 48)
    gemm_mfma<256, 4, 1, 3, 2, false, 0, false><<<dim3(391), blk, 0, stream>>>(
        bufZ, w1f, nullptr, b0, nullptr, g4, NN, 48);
    // spmm3 + b1 + log_softmax -> out
    spmm40_lsm<<<dim3(gSp), blk, 0, stream>>>(rp, edges, g4, b1, out);
    // l2 scalar
    finalize_l2<<<dim3(1), blk, 0, stream>>>(partials, 6250, out);
}

// Round 6
// 567.656 us; speedup vs baseline: 20.0508x; 1.1021x over previous
//
#include <hip/hip_runtime.h>
#include <math.h>

constexpr int NN = 100000;
constexpr int NCHUNK = 128;
constexpr int RROWS  = 12500;   // rows per range (8 ranges); 16-bit counters

using f32x4 = __attribute__((ext_vector_type(4))) float;
using s16x8 = __attribute__((ext_vector_type(8))) short;
using us8   = __attribute__((ext_vector_type(8))) unsigned short;

__device__ __forceinline__ unsigned short f2bf(float f) {
    unsigned u = __float_as_uint(f);
    unsigned r = u + 0x7FFFu + ((u >> 16) & 1u);
    return (unsigned short)(r >> 16);
}
__device__ __forceinline__ float bf2f(unsigned short u) {
    return __uint_as_float(((unsigned)u) << 16);
}

// ---------------------------------------------------------------------------
// Pack weight W[K x NC] (fp32) -> MFMA B-fragment order bf16, padded to NCpad.
// ---------------------------------------------------------------------------
__global__ __launch_bounds__(256) void wfrag_k(
    const float* __restrict__ W, short* __restrict__ Wf, int K, int NC, int NCpad)
{
    const int KK = K / 32;
    int total = (NCpad / 16) * KK * 64;
    int tid = blockIdx.x * 256 + threadIdx.x;
    if (tid >= total) return;
    int lane = tid & 63, f = tid >> 6;
    int ncg = f / KK, kk = f % KK;
    int col = ncg * 16 + (lane & 15);
    int k0  = kk * 32 + 8 * (lane >> 4);
    s16x8 o;
    #pragma unroll
    for (int j = 0; j < 8; ++j)
        o[j] = (col < NC) ? (short)f2bf(W[(size_t)(k0 + j) * NC + col]) : (short)0;
    *reinterpret_cast<s16x8*>(Wf + (size_t)tid * 8) = o;
}

// ---------------------------------------------------------------------------
// MFMA GEMM: C[M x NCout] = act(A[M x K] @ W + bias-term)
// AK: 0 = A fp32, 1 = A bf16, 2 = A bf16 with relu(a + b0[k])
// BIASMODE: 0 none, 1 +bias[col], 2 +rowsum[row]*bias[col]
// ---------------------------------------------------------------------------
template<int K, int WM, int WN, int CB, int AK, bool OBF16, int BIASMODE, bool ORELU>
__global__ __launch_bounds__(WM * WN * 64) void gemm_mfma(
    const void* __restrict__ Ain, const short* __restrict__ Wf,
    const float* __restrict__ bias, const float* __restrict__ b0,
    const float* __restrict__ rowsum, void* __restrict__ Cout, int M, int NCout)
{
    constexpr int KK = K / 32;
    const int tid = threadIdx.x;
    const int lane = tid & 63, wid = tid >> 6;
    const int wm = wid % WM, wn = wid / WM;
    const int rowBase = blockIdx.x * (WM * 64) + wm * 64;
    const int cfb = wn * CB;
    const int l15 = lane & 15, lh = lane >> 4;

    f32x4 acc[4][CB];
    #pragma unroll
    for (int i = 0; i < 4; ++i)
        #pragma unroll
        for (int j = 0; j < CB; ++j) acc[i][j] = (f32x4)0.f;

    #pragma unroll
    for (int kk = 0; kk < KK; ++kk) {
        const int k0 = kk * 32 + lh * 8;
        s16x8 a[4];
        #pragma unroll
        for (int rb = 0; rb < 4; ++rb) {
            int row = rowBase + rb * 16 + l15;
            row = row < M ? row : M - 1;
            if (AK == 0) {
                const float* ap = (const float*)Ain + (size_t)row * K + k0;
                float4 u = *reinterpret_cast<const float4*>(ap);
                float4 v = *reinterpret_cast<const float4*>(ap + 4);
                a[rb][0] = (short)f2bf(u.x); a[rb][1] = (short)f2bf(u.y);
                a[rb][2] = (short)f2bf(u.z); a[rb][3] = (short)f2bf(u.w);
                a[rb][4] = (short)f2bf(v.x); a[rb][5] = (short)f2bf(v.y);
                a[rb][6] = (short)f2bf(v.z); a[rb][7] = (short)f2bf(v.w);
            } else if (AK == 1) {
                a[rb] = *reinterpret_cast<const s16x8*>((const short*)Ain + (size_t)row * K + k0);
            } else {
                s16x8 s = *reinterpret_cast<const s16x8*>((const short*)Ain + (size_t)row * K + k0);
                float4 ba = *reinterpret_cast<const float4*>(b0 + k0);
                float4 bb = *reinterpret_cast<const float4*>(b0 + k0 + 4);
                float bv[8] = {ba.x, ba.y, ba.z, ba.w, bb.x, bb.y, bb.z, bb.w};
                #pragma unroll
                for (int j = 0; j < 8; ++j) {
                    float fv = bf2f((unsigned short)s[j]) + bv[j];
                    a[rb][j] = (short)f2bf(fmaxf(fv, 0.f));
                }
            }
        }
        s16x8 b[CB];
        #pragma unroll
        for (int cb = 0; cb < CB; ++cb)
            b[cb] = *reinterpret_cast<const s16x8*>(
                Wf + ((size_t)((cfb + cb) * KK + kk) * 64 + lane) * 8);
        #pragma unroll
        for (int rb = 0; rb < 4; ++rb)
            #pragma unroll
            for (int cb = 0; cb < CB; ++cb)
                acc[rb][cb] = __builtin_amdgcn_mfma_f32_16x16x32_bf16(
                    a[rb], b[cb], acc[rb][cb], 0, 0, 0);
    }

    #pragma unroll
    for (int cb = 0; cb < CB; ++cb) {
        int col = (cfb + cb) * 16 + l15;
        if (col >= NCout) continue;
        float bs = (BIASMODE != 0) ? bias[col] : 0.f;
        #pragma unroll
        for (int rb = 0; rb < 4; ++rb) {
            #pragma unroll
            for (int r = 0; r < 4; ++r) {
                int row = rowBase + rb * 16 + lh * 4 + r;
                if (row >= M) continue;
                float v = acc[rb][cb][r];
                if (BIASMODE == 1) v += bs;
                if (BIASMODE == 2) v += rowsum[row] * bs;
                if (ORELU) v = fmaxf(v, 0.f);
                if (OBF16)
                    ((unsigned short*)Cout)[(size_t)row * NCout + col] = f2bf(v);
                else
                    ((float*)Cout)[(size_t)row * NCout + col] = v;
            }
        }
    }
}

// ---------------------------------------------------------------------------
// Atomic-free CSR build with 16-bit packed LDS counters (2 rows per u32).
// ---------------------------------------------------------------------------
__global__ __launch_bounds__(256) void hist_part(
    const int* __restrict__ row, int* __restrict__ part, int E, int chunkE)
{
    __shared__ unsigned lcnt[RROWS / 2];
    const int chunk = blockIdx.x;
    const int rowLo = blockIdx.y * RROWS;
    for (int i = threadIdx.x; i < RROWS / 2; i += 256) lcnt[i] = 0u;
    __syncthreads();
    const int e0 = chunk * chunkE;
    const int e1 = min(e0 + chunkE, E);
    for (int e = e0 + threadIdx.x; e < e1; e += 256) {
        int lr = row[e] - rowLo;
        if ((unsigned)lr < (unsigned)RROWS)
            atomicAdd(&lcnt[lr >> 1], 1u << ((lr & 1) << 4));
    }
    __syncthreads();
    int2* dst = reinterpret_cast<int2*>(part + (size_t)chunk * NN + rowLo);
    for (int i = threadIdx.x; i < RROWS / 2; i += 256) {
        unsigned w = lcnt[i];
        dst[i] = make_int2((int)(w & 0xFFFFu), (int)(w >> 16));
    }
}

// Per-row running prefix across chunks (in place) + total -> cnt.
__global__ __launch_bounds__(256) void chunk_scan(
    int* __restrict__ part, int* __restrict__ cnt)
{
    int r = blockIdx.x * 256 + threadIdx.x;
    if (r >= NN) return;
    int run = 0;
    #pragma unroll 8
    for (int c = 0; c < NCHUNK; ++c) {
        int* p = part + (size_t)c * NN + r;
        int v = *p;
        *p = run;
        run += v;
    }
    cnt[r] = run;
}

__global__ __launch_bounds__(256) void scan_blk(
    const int* __restrict__ cnt, int* __restrict__ rp, int* __restrict__ bsums, int n)
{
    const int t = threadIdx.x;
    const int lane = t & 63, wid = t >> 6;
    const int base = blockIdx.x * 1024 + t * 4;
    int a0 = 0, a1 = 0, a2 = 0, a3 = 0;
    if (base + 3 < n) {
        int4 v = *reinterpret_cast<const int4*>(&cnt[base]);
        a0 = v.x; a1 = v.y; a2 = v.z; a3 = v.w;
    } else {
        if (base + 0 < n) a0 = cnt[base + 0];
        if (base + 1 < n) a1 = cnt[base + 1];
        if (base + 2 < n) a2 = cnt[base + 2];
        if (base + 3 < n) a3 = cnt[base + 3];
    }
    int s0 = a0, s1 = s0 + a1, s2 = s1 + a2, s3 = s2 + a3;
    int v = s3;
    #pragma unroll
    for (int o = 1; o < 64; o <<= 1) {
        int u = __shfl_up(v, o);
        if (lane >= o) v += u;
    }
    __shared__ int wtot[4];
    if (lane == 63) wtot[wid] = v;
    __syncthreads();
    int woff = 0;
    #pragma unroll
    for (int w = 0; w < 4; ++w) if (w < wid) woff += wtot[w];
    int texcl = woff + v - s3;
    if (base + 0 < n) rp[base + 0] = texcl;
    if (base + 1 < n) rp[base + 1] = texcl + s0;
    if (base + 2 < n) rp[base + 2] = texcl + s1;
    if (base + 3 < n) rp[base + 3] = texcl + s2;
    if (t == 255) bsums[blockIdx.x] = woff + v;
}

__global__ void scan_mid(const int* __restrict__ bsums, int* __restrict__ boff, int nb)
{
    if (threadIdx.x == 0 && blockIdx.x == 0) {
        int run = 0;
        for (int b = 0; b < nb; ++b) { boff[b] = run; run += bsums[b]; }
    }
}

__global__ __launch_bounds__(256) void scan_add(
    int* __restrict__ rp, const int* __restrict__ boff, int n, int E)
{
    int i = blockIdx.x * 256 + threadIdx.x;
    if (i < n) rp[i] += boff[i >> 10];
    if (i == 0) rp[n] = E;
}

// scatter with packed 16-bit LDS position counters (no global atomics).
__global__ __launch_bounds__(256) void scatter_part(
    const int* __restrict__ row, const int* __restrict__ col,
    const float* __restrict__ val, const int* __restrict__ rp,
    const int* __restrict__ part, int2* __restrict__ edges, int E, int chunkE)
{
    __shared__ unsigned lcnt[RROWS / 2];
    const int chunk = blockIdx.x;
    const int rowLo = blockIdx.y * RROWS;
    for (int i = threadIdx.x; i < RROWS / 2; i += 256) lcnt[i] = 0u;
    __syncthreads();
    const int e0 = chunk * chunkE;
    const int e1 = min(e0 + chunkE, E);
    const int* choff = part + (size_t)chunk * NN;
    for (int e = e0 + threadIdx.x; e < e1; e += 256) {
        int r = row[e];
        int lr = r - rowLo;
        if ((unsigned)lr < (unsigned)RROWS) {
            unsigned old = atomicAdd(&lcnt[lr >> 1], 1u << ((lr & 1) << 4));
            int local = (int)((old >> ((lr & 1) << 4)) & 0xFFFFu);
            int p = rp[r] + choff[r] + local;
            edges[p] = make_int2(col[e], __float_as_int(val[e]));
        }
    }
}

// ---------------------------------------------------------------------------
// CSR SpMM gather, F=128 bf16: 16 lanes per row (4 rows/wave), ushort8/lane.
// Edge loop unrolled x4 for memory-level parallelism.
// RS: also emit rowsum[r] (lane sl==0).
// ---------------------------------------------------------------------------
template<bool RS>
__global__ __launch_bounds__(256) void spmm128(
    const int* __restrict__ rp, const int2* __restrict__ edges,
    const unsigned short* __restrict__ mat, unsigned short* __restrict__ out,
    float* __restrict__ rowsum)
{
    int gid = blockIdx.x * 256 + threadIdx.x;
    int r = gid >> 4, sl = gid & 15;
    if (r >= NN) return;
    const int beg = rp[r], end = rp[r + 1];
    float acc[8] = {};
    float vs = 0.f;
    int e = beg;
    for (; e + 3 < end; e += 4) {
        int2 c0 = edges[e + 0], c1 = edges[e + 1];
        int2 c2 = edges[e + 2], c3 = edges[e + 3];
        float v0 = __int_as_float(c0.y), v1 = __int_as_float(c1.y);
        float v2 = __int_as_float(c2.y), v3 = __int_as_float(c3.y);
        us8 f0 = *reinterpret_cast<const us8*>(mat + (size_t)c0.x * 128 + sl * 8);
        us8 f1 = *reinterpret_cast<const us8*>(mat + (size_t)c1.x * 128 + sl * 8);
        us8 f2 = *reinterpret_cast<const us8*>(mat + (size_t)c2.x * 128 + sl * 8);
        us8 f3 = *reinterpret_cast<const us8*>(mat + (size_t)c3.x * 128 + sl * 8);
        if (RS) vs += v0 + v1 + v2 + v3;
        #pragma unroll
        for (int j = 0; j < 8; ++j)
            acc[j] += v0 * bf2f(f0[j]) + v1 * bf2f(f1[j])
                    + v2 * bf2f(f2[j]) + v3 * bf2f(f3[j]);
    }
    for (; e < end; ++e) {
        int2 cv = edges[e];
        float v = __int_as_float(cv.y);
        if (RS) vs += v;
        us8 f = *reinterpret_cast<const us8*>(mat + (size_t)cv.x * 128 + sl * 8);
        #pragma unroll
        for (int j = 0; j < 8; ++j) acc[j] += v * bf2f(f[j]);
    }
    us8 o;
    #pragma unroll
    for (int j = 0; j < 8; ++j) o[j] = f2bf(acc[j]);
    *reinterpret_cast<us8*>(out + (size_t)r * 128 + sl * 8) = o;
    if (RS && sl == 0) rowsum[r] = vs;
}

// ---------------------------------------------------------------------------
// Sampling from z[N x 256] bf16: h = mean + (softplus(s)+0.01)*eps, l2 partials.
// ---------------------------------------------------------------------------
__global__ __launch_bounds__(256) void sample_k(
    const unsigned short* __restrict__ z, const float* __restrict__ eps,
    unsigned short* __restrict__ h, float* __restrict__ partials)
{
    int idx = blockIdx.x * 256 + threadIdx.x;
    int r = idx >> 4, j = idx & 15;
    const unsigned short* zr = z + (size_t)r * 256 + j * 8;
    us8 mz = *reinterpret_cast<const us8*>(zr);
    us8 sz = *reinterpret_cast<const us8*>(zr + 128);
    const float* ep = eps + (size_t)r * 128 + j * 8;
    float4 e0 = *reinterpret_cast<const float4*>(ep);
    float4 e1 = *reinterpret_cast<const float4*>(ep + 4);
    float ev[8] = {e0.x, e0.y, e0.z, e0.w, e1.x, e1.y, e1.z, e1.w};
    float p = 0.f;
    us8 hv;
    #pragma unroll
    for (int k = 0; k < 8; ++k) {
        float mean = bf2f(mz[k]);
        float s    = bf2f(sz[k]);
        float sp   = fmaxf(s, 0.f) + log1pf(expf(-fabsf(s)));
        float sd   = sp + 0.01f;
        float hh   = mean + sd * ev[k];
        hv[k] = f2bf(hh);
        p += 0.5f * hh * hh - 0.5f * ev[k] * ev[k] - logf(sd);
    }
    *reinterpret_cast<us8*>(h + (size_t)r * 128 + j * 8) = hv;
    #pragma unroll
    for (int o = 32; o > 0; o >>= 1) p += __shfl_xor(p, o);
    __shared__ float ws[4];
    if ((threadIdx.x & 63) == 0) ws[threadIdx.x >> 6] = p;
    __syncthreads();
    if (threadIdx.x == 0)
        partials[blockIdx.x] = ws[0] + ws[1] + ws[2] + ws[3];
}

// ---------------------------------------------------------------------------
// CSR SpMM F=40 (fp32, stride 40) + b1 + log_softmax: 16 lanes/row, float4.
// ---------------------------------------------------------------------------
__global__ __launch_bounds__(256) void spmm40_lsm(
    const int* __restrict__ rp, const int2* __restrict__ edges,
    const float* __restrict__ mat, const float* __restrict__ b1,
    float* __restrict__ out)
{
    int gid = blockIdx.x * 256 + threadIdx.x;
    int r = gid >> 4, sl = gid & 15;
    const int beg = rp[r], end = rp[r + 1];
    float4 acc = make_float4(0.f, 0.f, 0.f, 0.f);
    int e = beg;
    for (; e + 3 < end; e += 4) {
        int2 c0 = edges[e + 0], c1 = edges[e + 1];
        int2 c2 = edges[e + 2], c3 = edges[e + 3];
        if (sl < 10) {
            float v0 = __int_as_float(c0.y), v1 = __int_as_float(c1.y);
            float v2 = __int_as_float(c2.y), v3 = __int_as_float(c3.y);
            float4 m0 = *reinterpret_cast<const float4*>(mat + (size_t)c0.x * 40 + sl * 4);
            float4 m1 = *reinterpret_cast<const float4*>(mat + (size_t)c1.x * 40 + sl * 4);
            float4 m2 = *reinterpret_cast<const float4*>(mat + (size_t)c2.x * 40 + sl * 4);
            float4 m3 = *reinterpret_cast<const float4*>(mat + (size_t)c3.x * 40 + sl * 4);
            acc.x += v0 * m0.x + v1 * m1.x + v2 * m2.x + v3 * m3.x;
            acc.y += v0 * m0.y + v1 * m1.y + v2 * m2.y + v3 * m3.y;
            acc.z += v0 * m0.z + v1 * m1.z + v2 * m2.z + v3 * m3.z;
            acc.w += v0 * m0.w + v1 * m1.w + v2 * m2.w + v3 * m3.w;
        }
    }
    for (; e < end; ++e) {
        int2 cv = edges[e];
        float v = __int_as_float(cv.y);
        if (sl < 10) {
            float4 m4 = *reinterpret_cast<const float4*>(mat + (size_t)cv.x * 40 + sl * 4);
            acc.x += v * m4.x; acc.y += v * m4.y; acc.z += v * m4.z; acc.w += v * m4.w;
        }
    }
    float xv[4] = {-1e30f, -1e30f, -1e30f, -1e30f};
    if (sl < 10) {
        xv[0] = acc.x + b1[sl * 4 + 0]; xv[1] = acc.y + b1[sl * 4 + 1];
        xv[2] = acc.z + b1[sl * 4 + 2]; xv[3] = acc.w + b1[sl * 4 + 3];
    }
    float m = fmaxf(fmaxf(xv[0], xv[1]), fmaxf(xv[2], xv[3]));
    #pragma unroll
    for (int o = 1; o < 16; o <<= 1) m = fmaxf(m, __shfl_xor(m, o, 16));
    float ssum = 0.f;
    #pragma unroll
    for (int k = 0; k < 4; ++k) ssum += (sl < 10) ? expf(xv[k] - m) : 0.f;
    #pragma unroll
    for (int o = 1; o < 16; o <<= 1) ssum += __shfl_xor(ssum, o, 16);
    if (sl < 10) {
        float lse = m + logf(ssum);
        float4 o4 = make_float4(xv[0] - lse, xv[1] - lse, xv[2] - lse, xv[3] - lse);
        *reinterpret_cast<float4*>(out + (size_t)r * 40 + sl * 4) = o4;
    }
}

__global__ __launch_bounds__(256) void finalize_l2(
    const float* __restrict__ partials, int np, float* __restrict__ out)
{
    double a = 0.0;
    for (int i = threadIdx.x; i < np; i += 256) a += (double)partials[i];
    #pragma unroll
    for (int o = 32; o > 0; o >>= 1) a += __shfl_xor(a, o);
    __shared__ double ws[4];
    if ((threadIdx.x & 63) == 0) ws[threadIdx.x >> 6] = a;
    __syncthreads();
    if (threadIdx.x == 0)
        out[(size_t)NN * 40] = (float)((ws[0] + ws[1] + ws[2] + ws[3]) / (double)NN);
}

// ---------------------------------------------------------------------------
extern "C" void kernel_launch(void* const* d_in, const int* in_sizes, int n_in,
                              void* d_out, int out_size, void* d_ws, size_t ws_size,
                              hipStream_t stream)
{
    const float* x    = (const float*)d_in[0];
    const int*   arow = (const int*)d_in[1];
    const int*   acol = (const int*)d_in[2];
    const float* aval = (const float*)d_in[3];
    const float* eps  = (const float*)d_in[4];
    const float* Wz1  = (const float*)d_in[5];
    const float* bz1  = (const float*)d_in[6];
    const float* Wz2  = (const float*)d_in[7];
    const float* bz2  = (const float*)d_in[8];
    const float* W0   = (const float*)d_in[9];
    const float* b0   = (const float*)d_in[10];
    const float* W1   = (const float*)d_in[11];
    const float* b1   = (const float*)d_in[12];
    float* out = (float*)d_out;
    const int E = in_sizes[1];

    // ---- workspace ----
    char* p = (char*)d_ws;
    auto alloc = [&](size_t bytes) {
        char* q = p;
        p += (bytes + 15) & ~(size_t)15;
        return (void*)q;
    };
    int2* edges    = (int2*)alloc((size_t)E * 8);
    int*  part     = (int*)alloc((size_t)NCHUNK * NN * 4);   // 51.2 MB
    int*  rp       = (int*)alloc((size_t)(NN + 4) * 4);
    int*  cnt      = (int*)alloc((size_t)NN * 4);
    float* rowsum  = (float*)alloc((size_t)NN * 4);
    int*  bsums    = (int*)alloc(128 * 4);
    int*  boff     = (int*)alloc(128 * 4);
    float* partials = (float*)alloc(6250 * 4);
    unsigned short* bufT = (unsigned short*)alloc((size_t)NN * 128 * 2); // t1 / ah
    unsigned short* bufU = (unsigned short*)alloc((size_t)NN * 128 * 2); // at1 / h
    unsigned short* bufZ = (unsigned short*)alloc((size_t)NN * 256 * 2); // z / s2
    float* g4      = (float*)alloc((size_t)NN * 40 * 4);
    short* wz1f    = (short*)alloc(8  * 4 * 64 * 8 * 2);
    short* wz2f    = (short*)alloc(16 * 4 * 64 * 8 * 2);
    short* w0f     = (short*)alloc(16 * 4 * 64 * 8 * 2);
    short* w1f     = (short*)alloc(3  * 8 * 64 * 8 * 2);

    dim3 blk(256);
    const int nScan = (NN + 1023) / 1024;
    const int gSp = (NN * 16) / 256;                 // 6250
    const int chunkE = (E + NCHUNK - 1) / NCHUNK;    // 12500
    const dim3 gPart(NCHUNK, NN / RROWS);            // 128 x 8

    // --- weight fragment packing ---
    wfrag_k<<<dim3((8  * 4 * 64 + 255) / 256), blk, 0, stream>>>(Wz1, wz1f, 128, 128, 128);
    wfrag_k<<<dim3((16 * 4 * 64 + 255) / 256), blk, 0, stream>>>(Wz2, wz2f, 128, 256, 256);
    wfrag_k<<<dim3((16 * 4 * 64 + 255) / 256), blk, 0, stream>>>(W0,  w0f,  128, 256, 256);
    wfrag_k<<<dim3((3  * 8 * 64 + 255) / 256), blk, 0, stream>>>(W1,  w1f,  256, 40, 48);

    // --- CSR build (atomic-free, 16-bit packed LDS counters) ---
    hist_part<<<gPart, blk, 0, stream>>>(arow, part, E, chunkE);
    chunk_scan<<<dim3((NN + 255) / 256), blk, 0, stream>>>(part, cnt);
    scan_blk<<<dim3(nScan), blk, 0, stream>>>(cnt, rp, bsums, NN);
    scan_mid<<<dim3(1), dim3(64), 0, stream>>>(bsums, boff, nScan);
    scan_add<<<dim3((NN + 256) / 256), blk, 0, stream>>>(rp, boff, NN, E);
    scatter_part<<<gPart, blk, 0, stream>>>(arow, acol, aval, rp, part, edges, E, chunkE);

    // --- pipeline ---
    // G1: t1 = relu(x@Wz1 + bz1) -> bufT (N x 128 bf16)
    gemm_mfma<128, 2, 2, 4, 0, true, 1, true><<<dim3(782), blk, 0, stream>>>(
        x, wz1f, bz1, nullptr, nullptr, bufT, NN, 128);
    // at1 = S @ t1 -> bufU  (also emits rowsum)
    spmm128<true><<<dim3(gSp), blk, 0, stream>>>(rp, edges, bufT, bufU, rowsum);
    // z = at1@Wz2 + rowsum*bz2 -> bufZ (N x 256 bf16)
    gemm_mfma<128, 1, 4, 4, 1, true, 2, false><<<dim3(1563), blk, 0, stream>>>(
        bufU, wz2f, bz2, nullptr, rowsum, bufZ, NN, 256);
    // sample: h -> bufU, l2 partials
    sample_k<<<dim3(gSp), blk, 0, stream>>>(bufZ, eps, bufU, partials);
    // ah = S @ h -> bufT
    spmm128<false><<<dim3(gSp), blk, 0, stream>>>(rp, edges, bufU, bufT, nullptr);
    // s2 = ah@W0 -> bufZ
    gemm_mfma<128, 1, 4, 4, 1, true, 0, false><<<dim3(1563), blk, 0, stream>>>(
        bufT, w0f, nullptr, nullptr, nullptr, bufZ, NN, 256);
    // g4 = relu(s2 + b0)@W1 -> fp32 (N x 40)
    gemm_mfma<256, 4, 1, 3, 2, false, 0, false><<<dim3(391), blk, 0, stream>>>(
        bufZ, w1f, nullptr, b0, nullptr, g4, NN, 40);
    // spmm3 + b1 + log_softmax -> out
    spmm40_lsm<<<dim3(gSp), blk, 0, stream>>>(rp, edges, g4, b1, out);
    // l2 scalar
    finalize_l2<<<dim3(1), blk, 0, stream>>>(partials, 6250, out);
}